// Round 12
// baseline (162.064 us; speedup 1.0000x reference)
//
#include <hip/hip_runtime.h>
#include <cstdint>
#include <cstddef>

#define N_ROWS 2048
#define D_DIM  1024

typedef __bf16 bf16x8 __attribute__((ext_vector_type(8)));
typedef float  f32x4  __attribute__((ext_vector_type(4)));

__device__ __forceinline__ unsigned short f2bf(float f) {
    unsigned int u = __float_as_uint(f);
    unsigned int r = (u + 0x7fffu + ((u >> 16) & 1u)) >> 16;   // RNE
    return (unsigned short)r;
}
__device__ __forceinline__ float bf2f(unsigned short u) {
    return __uint_as_float(((unsigned int)u) << 16);
}
__device__ __forceinline__ void gload_lds16(const void* g, void* lds) {
    __builtin_amdgcn_global_load_lds(
        (const __attribute__((address_space(1))) unsigned int*)g,
        (__attribute__((address_space(3))) unsigned int*)lds, 16, 0, 0);
}

template<int N> __device__ __forceinline__ void wait_vmcnt();
template<> __device__ __forceinline__ void wait_vmcnt<0>() { asm volatile("s_waitcnt vmcnt(0)" ::: "memory"); }
template<> __device__ __forceinline__ void wait_vmcnt<2>() { asm volatile("s_waitcnt vmcnt(2)" ::: "memory"); }
template<> __device__ __forceinline__ void wait_vmcnt<4>() { asm volatile("s_waitcnt vmcnt(4)" ::: "memory"); }
template<> __device__ __forceinline__ void wait_vmcnt<6>() { asm volatile("s_waitcnt vmcnt(6)" ::: "memory"); }
template<> __device__ __forceinline__ void wait_vmcnt<8>() { asm volatile("s_waitcnt vmcnt(8)" ::: "memory"); }

// ---------------------------------------------------------------------------
// fused fp32->bf16 convert of all five weight tensors (blocks 0..2047)
// + dtype sniff / normalize of targets & mask (block 2048)
// ---------------------------------------------------------------------------
__global__ __launch_bounds__(256) void cvt_all_kernel(
    const float* __restrict__ s0, unsigned short* __restrict__ d0,  // headW  4002*1024
    const float* __restrict__ s1, unsigned short* __restrict__ d1,  // t0out 16000*256
    const float* __restrict__ s2, unsigned short* __restrict__ d2,  // t1out 30000*64
    const float* __restrict__ s3, unsigned short* __restrict__ d3,  // t0proj  256*1024
    const float* __restrict__ s4, unsigned short* __restrict__ d4,  // t1proj   64*1024
    const unsigned char* __restrict__ traw,
    const unsigned char* __restrict__ mraw,
    int* __restrict__ tgt32, int* __restrict__ mask32)
{
    const int tid = threadIdx.x;
    if (blockIdx.x == 2048) {
        __shared__ int fFloat, fByte, fOdd;
        if (tid == 0) { fFloat = 0; fByte = 0; fOdd = 0; }
        __syncthreads();
        const unsigned int* mw = (const unsigned int*)mraw;
        for (int i = tid; i < 512; i += 256) {
            unsigned int w = mw[i];
            if (w == 0x3f800000u) atomicOr(&fFloat, 1);
            if (w & 0xFFFFFF00u)  atomicOr(&fByte, 1);
        }
        const unsigned int* tw = (const unsigned int*)traw;
        for (int i = tid; i < N_ROWS; i += 256) {
            if ((i & 1) && tw[i] != 0u) atomicOr(&fOdd, 1);
        }
        __syncthreads();
        const int mlayout = fFloat ? 2 : (fByte ? 1 : 0);
        const int tis64   = fOdd ? 0 : 1;
        for (int i = tid; i < N_ROWS; i += 256) {
            long long t = tis64 ? ((const long long*)traw)[i]
                                : (long long)((const int*)traw)[i];
            tgt32[i] = (int)t;
            int m;
            if (mlayout == 1) m = (mraw[i] != 0);
            else              m = (((const unsigned int*)mraw)[i] != 0u);
            mask32[i] = m;
        }
        return;
    }
    const int total = 2610432;  // vec4 units
    for (int i = blockIdx.x * 256 + tid; i < total; i += 2048 * 256) {
        const float* s; unsigned short* d; int off;
        if (i < 1024512)      { s = s0; d = d0; off = i; }
        else if (i < 2048512) { s = s1; d = d1; off = i - 1024512; }
        else if (i < 2528512) { s = s2; d = d2; off = i - 2048512; }
        else if (i < 2594048) { s = s3; d = d3; off = i - 2528512; }
        else                  { s = s4; d = d4; off = i - 2594048; }
        float4 v = ((const float4*)s)[off];
        ushort4 o;
        o.x = f2bf(v.x); o.y = f2bf(v.y); o.z = f2bf(v.z); o.w = f2bf(v.w);
        ((ushort4*)d)[off] = o;
    }
}

// ---------------------------------------------------------------------------
// gather + fp32->bf16: emb[n] = replace ? cls[b] : lhs[b,tok]
// ---------------------------------------------------------------------------
__global__ __launch_bounds__(256) void gather_cvt_kernel(
    const float* __restrict__ lhs, const float* __restrict__ cls,
    const int* __restrict__ bids, const int* __restrict__ toks,
    const int* __restrict__ mask32, unsigned short* __restrict__ emb)
{
    const int n = blockIdx.x;
    const int b = bids[n];
    const int tok = toks[n];
    const float* src = mask32[n] ? (cls + (size_t)b * D_DIM)
                                 : (lhs + ((size_t)b * 512 + (size_t)tok) * D_DIM);
    float4 v = ((const float4*)src)[threadIdx.x];
    ushort4 o;
    o.x = f2bf(v.x); o.y = f2bf(v.y); o.z = f2bf(v.z); o.w = f2bf(v.w);
    ((ushort4*)(emb + (size_t)n * D_DIM))[threadIdx.x] = o;
}

// sum 4 split-K partials, split h01 [2048][320] -> h0 bf16 [2048][256], h1 [2048][64]
__global__ __launch_bounds__(256) void cvt_h01_kernel(
    const float* __restrict__ h01p, unsigned short* __restrict__ h0,
    unsigned short* __restrict__ h1)
{
    const int idx = blockIdx.x * 256 + threadIdx.x;
    if (idx >= 2048 * 320) return;
    const float v = h01p[idx] + h01p[655360 + idx] + h01p[1310720 + idx]
                  + h01p[1966080 + idx];
    const int r = idx / 320;
    const int c = idx - r * 320;
    const unsigned short b = f2bf(v);
    if (c < 256) h0[r * 256 + c] = b;
    else         h1[r * 64 + (c - 256)] = b;
}

// ---------------------------------------------------------------------------
// MERGED head+tail0 GEMM: 8 waves, <128,256>, 3-deep LDS ring, ONE barrier
// per K-tile (R11-proven schedule). Block-range segment select:
//   wg <  nblk0 : head  (A0/W0/bias, NT0, part0) + c0/c1 capture (by==15)
//   wg >= nblk0 : tail0 (A1/W1,     NT1, part1)
// Fused per-row sum(exp(logit+bias)) -> part[by*2048+row].
// ---------------------------------------------------------------------------
template<int BM, int BN>
__global__ __launch_bounds__(512, 2) void gemmHT_kernel(
    const unsigned short* __restrict__ A0, int K0,
    const unsigned short* __restrict__ W0, int C0,
    const float* __restrict__ bias0, float* __restrict__ part0, int NT0, int nblk0,
    const unsigned short* __restrict__ A1, int K1,
    const unsigned short* __restrict__ W1, int C1,
    float* __restrict__ part1, int NT1,
    float* __restrict__ c0cap, float* __restrict__ c1cap)
{
    constexpr int WM = BM / 2, WN = BN / 4;
    constexpr int MF = WM / 16, NF = WN / 16;
    constexpr int NA = BM / 64, NB = BN / 64;
    constexpr int L  = NA + NB;
    constexpr int ABYTES   = BM * 128;
    constexpr int BUFBYTES = (BM + BN) * 128;
    __shared__ char lds[3 * BUFBYTES];

    const int nwg = gridDim.x;
    const int lid = blockIdx.x;
    const int xcd = lid & 7, idx8 = lid >> 3;
    const int qq = nwg >> 3, rr = nwg & 7;
    const int wg = (xcd < rr ? xcd * (qq + 1) : rr * (qq + 1) + (xcd - rr) * qq) + idx8;

    // segment select (block-uniform)
    const unsigned short *A, *W;
    const float* bias;
    float* part;
    int K, C, NT;
    bool isHead;
    int swg;
    if (wg < nblk0) { A = A0; W = W0; bias = bias0; part = part0; K = K0; C = C0;
                      NT = NT0; isHead = true;  swg = wg; }
    else            { A = A1; W = W1; bias = nullptr; part = part1; K = K1; C = C1;
                      NT = NT1; isHead = false; swg = wg - nblk0; }
    const int bx = swg & 15;
    const int by = swg >> 4;

    const int tid = threadIdx.x;
    const int w = tid >> 6, l = tid & 63;
    const int wr = w >> 2, wc = w & 3;
    const int q16 = l >> 4, r16 = l & 15;
    const int rowA0 = bx * BM;
    const int cB = by * BN;

    const int srow = tid >> 3;
    const int sp   = (tid & 7) ^ (srow & 7);
    const unsigned short* aSrc[NA];
    const unsigned short* bSrc[NB];
    #pragma unroll
    for (int c = 0; c < NA; ++c)
        aSrc[c] = A + (size_t)(rowA0 + c * 64 + srow) * K + sp * 8;
    #pragma unroll
    for (int c = 0; c < NB; ++c) {
        int rbl = cB + c * 64 + srow;
        if (rbl >= C) rbl = C - 1;
        bSrc[c] = W + (size_t)rbl * K + sp * 8;
    }

    auto stage = [&](int kt, int buf) {
        char* base = lds + buf * BUFBYTES;
        #pragma unroll
        for (int c = 0; c < NA; ++c)
            gload_lds16(aSrc[c] + kt * 64, base + c * 8192 + (w << 10));
        #pragma unroll
        for (int c = 0; c < NB; ++c)
            gload_lds16(bSrc[c] + kt * 64, base + ABYTES + c * 8192 + (w << 10));
    };

    f32x4 acc[MF][NF];
    #pragma unroll
    for (int m = 0; m < MF; ++m)
        #pragma unroll
        for (int n = 0; n < NF; ++n) acc[m][n] = (f32x4){0.f, 0.f, 0.f, 0.f};

    stage(0, 0);
    if (NT > 1) stage(1, 1);

    for (int kt = 0; kt < NT; ++kt) {
        const int buf = kt % 3;
        if (kt + 1 < NT) wait_vmcnt<L>(); else wait_vmcnt<0>();
        __builtin_amdgcn_s_barrier();
        __builtin_amdgcn_sched_barrier(0);
        if (kt + 2 < NT) stage(kt + 2, (kt + 2) % 3);
        __builtin_amdgcn_sched_barrier(0);

        const char* Ab = lds + buf * BUFBYTES;
        const char* Bb = Ab + ABYTES;
        #pragma unroll
        for (int ks = 0; ks < 2; ++ks) {
            const int xs = ((ks * 4 + q16) ^ (l & 7)) << 4;
            bf16x8 af[MF], bv[NF];
            #pragma unroll
            for (int m = 0; m < MF; ++m)
                af[m] = *reinterpret_cast<const bf16x8*>(
                    Ab + (wr * WM + m * 16 + r16) * 128 + xs);
            #pragma unroll
            for (int n = 0; n < NF; ++n)
                bv[n] = *reinterpret_cast<const bf16x8*>(
                    Bb + (wc * WN + n * 16 + r16) * 128 + xs);
            __builtin_amdgcn_s_setprio(1);
            #pragma unroll
            for (int m = 0; m < MF; ++m)
                #pragma unroll
                for (int n = 0; n < NF; ++n)
                    acc[m][n] = __builtin_amdgcn_mfma_f32_16x16x32_bf16(
                        af[m], bv[n], acc[m][n], 0, 0, 0);
            __builtin_amdgcn_s_setprio(0);
        }
    }

    float bj[NF]; bool vj[NF];
    #pragma unroll
    for (int n = 0; n < NF; ++n) {
        const int c = cB + wc * WN + n * 16 + r16;
        vj[n] = (c < C);
        bj[n] = (vj[n] && bias) ? bias[c] : 0.f;
    }

    // head cluster-logit capture: only the block whose col range holds 4000/4001
    if (isHead && cB + BN > 4000) {          // block-uniform (cB==3840 only)
        #pragma unroll
        for (int n = 0; n < NF; ++n) {
            const int c = cB + wc * WN + n * 16 + r16;
            if (c == 4000 || c == 4001) {
                float* dst = (c == 4000) ? c0cap : c1cap;
                #pragma unroll
                for (int m = 0; m < MF; ++m)
                    #pragma unroll
                    for (int r = 0; r < 4; ++r) {
                        const int row = rowA0 + wr * WM + m * 16 + q16 * 4 + r;
                        dst[row] = acc[m][n][r] + bj[n];
                    }
            }
        }
    }

    __syncthreads();
    float* pl = (float*)lds;
    #pragma unroll
    for (int m = 0; m < MF; ++m)
        #pragma unroll
        for (int r = 0; r < 4; ++r) {
            float s = 0.f;
            #pragma unroll
            for (int n = 0; n < NF; ++n)
                if (vj[n]) s += __expf(acc[m][n][r] + bj[n]);
            s += __shfl_xor(s, 1); s += __shfl_xor(s, 2);
            s += __shfl_xor(s, 4); s += __shfl_xor(s, 8);
            if (r16 == 0)
                pl[wc * BM + wr * WM + m * 16 + q16 * 4 + r] = s;
        }
    __syncthreads();
    if (tid < BM)
        part[(size_t)by * N_ROWS + rowA0 + tid] =
            pl[tid] + pl[BM + tid] + pl[2 * BM + tid] + pl[3 * BM + tid];
}

// ---------------------------------------------------------------------------
// tail1 specialist: K=64 one tile -> pipeline along COLUMNS. A staged once,
// A-frags in registers; W streams through a 3-buf LDS ring (single barrier,
// counted vmcnt(2)). LDS 64KB -> 2 blocks/CU for inter-block overlap.
// ---------------------------------------------------------------------------
template<int CT>
__global__ __launch_bounds__(512, 4) void tail1_kernel(
    const unsigned short* __restrict__ A,   // [2048][64]
    const unsigned short* __restrict__ W,   // [C][64]
    float* __restrict__ part, int C)
{
    __shared__ char lds[65536];   // A @0 (16KB), W ring @16384 + buf*16384

    const int gx = gridDim.x, gy = gridDim.y;
    const int nwg = gx * gy;
    const int lid = blockIdx.x + gx * blockIdx.y;
    const int xcd = lid & 7, idx8 = lid >> 3;
    const int qq = nwg >> 3, rr = nwg & 7;
    const int wg = (xcd < rr ? xcd * (qq + 1) : rr * (qq + 1) + (xcd - rr) * qq) + idx8;
    const int bx = wg % gx;
    const int by = wg / gx;

    const int tid = threadIdx.x;
    const int w = tid >> 6, l = tid & 63;
    const int wr = w >> 2, wc = w & 3;      // WM=64 (MF=4), WN=32 (NF=2)
    const int q16 = l >> 4, r16 = l & 15;
    const int rowA0 = bx * 128;
    const int cB0 = by * (CT * 128);

    const int srow = tid >> 3;
    const int sp   = (tid & 7) ^ (srow & 7);

    #pragma unroll
    for (int c = 0; c < 2; ++c)
        gload_lds16(A + (size_t)(rowA0 + c * 64 + srow) * 64 + sp * 8,
                    lds + c * 8192 + (w << 10));

    auto stageW = [&](int ct, int buf) {
        char* base = lds + 16384 + buf * 16384;
        #pragma unroll
        for (int c = 0; c < 2; ++c) {
            int rw = cB0 + ct * 128 + c * 64 + srow;
            if (rw >= C) rw = C - 1;
            gload_lds16(W + (size_t)rw * 64 + sp * 8, base + c * 8192 + (w << 10));
        }
    };
    stageW(0, 0);
    if (CT > 1) stageW(1, 1);

    wait_vmcnt<4>();                 // own A loads (oldest 2) landed
    __builtin_amdgcn_s_barrier();    // -> all waves' A writes landed

    bf16x8 areg[2][4];
    #pragma unroll
    for (int ks = 0; ks < 2; ++ks)
        #pragma unroll
        for (int m = 0; m < 4; ++m) {
            const int row = wr * 64 + m * 16 + r16;
            const int xs = ((ks * 4 + q16) ^ (l & 7)) << 4;
            areg[ks][m] = *reinterpret_cast<const bf16x8*>(lds + row * 128 + xs);
        }

    float esum[4][4];
    #pragma unroll
    for (int m = 0; m < 4; ++m)
        #pragma unroll
        for (int r = 0; r < 4; ++r) esum[m][r] = 0.f;

    for (int ct = 0; ct < CT; ++ct) {
        const int buf = ct % 3;
        if (ct + 1 < CT) wait_vmcnt<2>(); else wait_vmcnt<0>();
        __builtin_amdgcn_s_barrier();
        __builtin_amdgcn_sched_barrier(0);
        if (ct + 2 < CT) stageW(ct + 2, (ct + 2) % 3);
        __builtin_amdgcn_sched_barrier(0);

        const char* Bb = lds + 16384 + buf * 16384;
        bf16x8 wreg[2][2];
        #pragma unroll
        for (int ks = 0; ks < 2; ++ks)
            #pragma unroll
            for (int n = 0; n < 2; ++n) {
                const int row = wc * 32 + n * 16 + r16;
                const int xs = ((ks * 4 + q16) ^ (l & 7)) << 4;
                wreg[ks][n] = *reinterpret_cast<const bf16x8*>(Bb + row * 128 + xs);
            }

        f32x4 acc[4][2];
        #pragma unroll
        for (int m = 0; m < 4; ++m)
            #pragma unroll
            for (int n = 0; n < 2; ++n) acc[m][n] = (f32x4){0.f, 0.f, 0.f, 0.f};

        __builtin_amdgcn_s_setprio(1);
        #pragma unroll
        for (int ks = 0; ks < 2; ++ks)
            #pragma unroll
            for (int m = 0; m < 4; ++m)
                #pragma unroll
                for (int n = 0; n < 2; ++n)
                    acc[m][n] = __builtin_amdgcn_mfma_f32_16x16x32_bf16(
                        areg[ks][m], wreg[ks][n], acc[m][n], 0, 0, 0);
        __builtin_amdgcn_s_setprio(0);

        bool vj[2];
        #pragma unroll
        for (int n = 0; n < 2; ++n)
            vj[n] = (cB0 + ct * 128 + wc * 32 + n * 16 + r16) < C;
        #pragma unroll
        for (int m = 0; m < 4; ++m)
            #pragma unroll
            for (int r = 0; r < 4; ++r) {
                float s = 0.f;
                #pragma unroll
                for (int n = 0; n < 2; ++n)
                    if (vj[n]) s += __expf(acc[m][n][r]);
                esum[m][r] += s;
            }
    }

    __syncthreads();
    float* pl = (float*)lds;
    #pragma unroll
    for (int m = 0; m < 4; ++m)
        #pragma unroll
        for (int r = 0; r < 4; ++r) {
            float v = esum[m][r];
            v += __shfl_xor(v, 1); v += __shfl_xor(v, 2);
            v += __shfl_xor(v, 4); v += __shfl_xor(v, 8);
            if (r16 == 0)
                pl[wc * 128 + wr * 64 + m * 16 + q16 * 4 + r] = v;
        }
    __syncthreads();
    if (tid < 128)
        part[(size_t)by * N_ROWS + rowA0 + tid] =
            pl[tid] + pl[128 + tid] + pl[256 + tid] + pl[384 + tid];
}

// ---------------------------------------------------------------------------
// proj GEMM (128-tile ring pipeline, split-K plain stores) — unchanged (proven)
// ---------------------------------------------------------------------------
template<int MODE>
__global__ __launch_bounds__(256) void gemm_pipe_kernel(
    const unsigned short* __restrict__ A, int K,
    const unsigned short* __restrict__ W, int C,
    float* __restrict__ outF, int kLen)
{
    __shared__ char lds[49152];

    const int gx = gridDim.x, gy = gridDim.y;
    const int nwg = gx * gy * gridDim.z;
    const int lid = blockIdx.x + gx * (blockIdx.y + gy * blockIdx.z);
    const int xcd = lid & 7, idx8 = lid >> 3;
    const int qq = nwg >> 3, rr = nwg & 7;
    const int wg = (xcd < rr ? xcd * (qq + 1) : rr * (qq + 1) + (xcd - rr) * qq) + idx8;
    const int bx = wg % gx;
    const int t1 = wg / gx;
    const int by = t1 % gy;
    const int bz = t1 / gy;

    const int tid = threadIdx.x;
    const int w = tid >> 6, l = tid & 63;
    const int wr = w >> 1, wc = w & 1;
    const int q16 = l >> 4, r16 = l & 15;
    const int rowA0 = bx << 7;
    const int kBeg = bz * kLen;

    const int sRl = (w << 5) + (l >> 2);
    const int sS  = l & 3;
    const int nt  = kLen >> 5;

    const unsigned short* aB[2];
    const unsigned short* wB[2];
    #pragma unroll
    for (int it = 0; it < 2; ++it) {
        const int R  = sRl + (it << 4);
        const int Sp = sS ^ ((R >> 1) & 3);
        aB[it] = A + (size_t)(rowA0 + R) * K + kBeg + Sp * 8;
        int Rw = (by << 7) + R; if (Rw >= C) Rw = C - 1;
        wB[it] = W + (size_t)Rw * K + kBeg + Sp * 8;
    }

    auto stage = [&](int ksv, int buf) {
        char* Ab = lds + buf * 16384;
        char* Wb = Ab + 8192;
        const int ko = ksv << 5;
        #pragma unroll
        for (int it = 0; it < 2; ++it) {
            gload_lds16(aB[it] + ko, Ab + (w << 11) + (it << 10));
            gload_lds16(wB[it] + ko, Wb + (w << 11) + (it << 10));
        }
    };

    f32x4 acc[4][4];
    #pragma unroll
    for (int m = 0; m < 4; ++m)
        #pragma unroll
        for (int n = 0; n < 4; ++n) acc[m][n] = (f32x4){0.f, 0.f, 0.f, 0.f};

    stage(0, 0); stage(1, 1); stage(2, 2);

    for (int s = 0; s < nt; ++s) {
        const int rem = nt - 1 - s;
        if (rem >= 2)      wait_vmcnt<8>();
        else if (rem == 1) wait_vmcnt<4>();
        else               wait_vmcnt<0>();
        __builtin_amdgcn_s_barrier();
        __builtin_amdgcn_sched_barrier(0);

        char* Ab = lds + (s % 3) * 16384;
        char* Wb = Ab + 8192;
        bf16x8 af[4], bfr[4];
        #pragma unroll
        for (int m = 0; m < 4; ++m) {
            const int row = (wr << 6) + (m << 4) + r16;
            af[m] = *reinterpret_cast<const bf16x8*>(
                Ab + row * 64 + ((q16 ^ ((row >> 1) & 3)) << 4));
        }
        #pragma unroll
        for (int n = 0; n < 4; ++n) {
            const int row = (wc << 6) + (n << 4) + r16;
            bfr[n] = *reinterpret_cast<const bf16x8*>(
                Wb + row * 64 + ((q16 ^ ((row >> 1) & 3)) << 4));
        }
        __builtin_amdgcn_sched_barrier(0);
        __builtin_amdgcn_s_barrier();

        if (s + 3 < nt) stage(s + 3, s % 3);

        __builtin_amdgcn_s_setprio(1);
        #pragma unroll
        for (int m = 0; m < 4; ++m)
            #pragma unroll
            for (int n = 0; n < 4; ++n)
                acc[m][n] = __builtin_amdgcn_mfma_f32_16x16x32_bf16(
                    af[m], bfr[n], acc[m][n], 0, 0, 0);
        __builtin_amdgcn_s_setprio(0);
    }

    float* o = outF + (size_t)bz * ((size_t)N_ROWS * C);
    #pragma unroll
    for (int n = 0; n < 4; ++n) {
        const int c = (by << 7) + (wc << 6) + (n << 4) + r16;
        if (c < C) {
            #pragma unroll
            for (int m = 0; m < 4; ++m)
                #pragma unroll
                for (int r = 0; r < 4; ++r) {
                    const int row = rowA0 + (wr << 6) + (m << 4) + (q16 << 2) + r;
                    o[(size_t)row * C + c] = acc[m][n][r];
                }
        }
    }
}

// ---------------------------------------------------------------------------
// slim per-row target-logit dot (one wave per row; single dot per row)
// ---------------------------------------------------------------------------
__global__ __launch_bounds__(256) void dot_kernel(
    const unsigned short* __restrict__ emb,
    const unsigned short* __restrict__ headW,
    const float* __restrict__ headB,
    const unsigned short* __restrict__ h0,
    const unsigned short* __restrict__ t0out,
    const unsigned short* __restrict__ h1,
    const unsigned short* __restrict__ t1out,
    const int* __restrict__ tgt32,
    float* __restrict__ tgtH, float* __restrict__ tg0, float* __restrict__ tg1)
{
    const int n = blockIdx.x * 4 + (threadIdx.x >> 6);
    const int l = threadIdx.x & 63;
    const int t = tgt32[n];

    float sv = 0.f;
    if (t < 4000) {
        const unsigned short* e  = emb + (size_t)n * 1024;
        const unsigned short* wt = headW + (size_t)t * 1024;
        for (int i = l; i < 1024; i += 64) sv += bf2f(e[i]) * bf2f(wt[i]);
    } else if (t < 20000) {
        const unsigned short* h  = h0 + (size_t)n * 256;
        const unsigned short* ww = t0out + (size_t)(t - 4000) * 256;
        for (int i = l; i < 256; i += 64) sv += bf2f(h[i]) * bf2f(ww[i]);
    } else {
        const unsigned short* h  = h1 + (size_t)n * 64;
        const unsigned short* ww = t1out + (size_t)(t - 20000) * 64;
        sv = bf2f(h[l]) * bf2f(ww[l]);
    }
    #pragma unroll
    for (int msk = 1; msk < 64; msk <<= 1) sv += __shfl_xor(sv, msk);
    if (l == 0) {
        if (t < 4000)       tgtH[n] = sv + headB[t];
        else if (t < 20000) tg0[n]  = sv;
        else                tg1[n]  = sv;
    }
}

// ---------------------------------------------------------------------------
// rowfinal: per-row reduce of the 3 partial arrays + log-softmax combine.
// grid 64 x 256 threads: 32 rows/block, 8 lanes/row. Also block loss partial.
// ---------------------------------------------------------------------------
__global__ __launch_bounds__(256) void rowfinal_kernel(
    const float* __restrict__ pH, const float* __restrict__ p0,
    const float* __restrict__ p1,
    const float* __restrict__ tgtH, const float* __restrict__ tg0,
    const float* __restrict__ tg1,
    const float* __restrict__ c0, const float* __restrict__ c1,
    const int* __restrict__ tgt32,
    float* __restrict__ out, float* __restrict__ lossPart)
{
    const int tid = threadIdx.x;
    const int rloc = tid >> 3, g = tid & 7;
    const int row = blockIdx.x * 32 + rloc;

    float sH = 0.f, s0 = 0.f, s1 = 0.f;
    for (int i = g; i < 16; i += 8) sH += pH[(size_t)i * N_ROWS + row];
    for (int i = g; i < 63; i += 8) s0 += p0[(size_t)i * N_ROWS + row];
    for (int i = g; i < 30; i += 8) s1 += p1[(size_t)i * N_ROWS + row];
    #pragma unroll
    for (int msk = 1; msk < 8; msk <<= 1) {
        sH += __shfl_xor(sH, msk);
        s0 += __shfl_xor(s0, msk);
        s1 += __shfl_xor(s1, msk);
    }
    __shared__ float sO[32];
    if (g == 0) {
        const int t = tgt32[row];
        const float lseH = logf(sH);
        float o;
        if (t < 4000)        o = tgtH[row] - lseH;
        else if (t < 20000)  o = (c0[row] - lseH) + tg0[row] - logf(s0);
        else                 o = (c1[row] - lseH) + tg1[row] - logf(s1);
        out[row] = o;
        sO[rloc] = o;
    }
    __syncthreads();
    if (tid < 64) {
        float v = (tid < 32) ? sO[tid] : 0.f;
        #pragma unroll
        for (int msk = 1; msk < 64; msk <<= 1) v += __shfl_xor(v, msk);
        if (tid == 0) lossPart[blockIdx.x] = v;
    }
}

// ---------------------------------------------------------------------------
__global__ __launch_bounds__(64) void finalize2_kernel(
    const float* __restrict__ lossPart, float* __restrict__ out)
{
    float v = lossPart[threadIdx.x];
    #pragma unroll
    for (int msk = 1; msk < 64; msk <<= 1) v += __shfl_xor(v, msk);
    if (threadIdx.x == 0) out[N_ROWS] = -v / (float)N_ROWS;
}

// ---------------------------------------------------------------------------
extern "C" void kernel_launch(void* const* d_in, const int* in_sizes, int n_in,
                              void* d_out, int out_size, void* d_ws, size_t ws_size,
                              hipStream_t stream)
{
    const unsigned char* traw = (const unsigned char*)d_in[0];
    const float* lhs    = (const float*)d_in[1];
    const float* cls    = (const float*)d_in[2];
    const int*   bids   = (const int*)d_in[3];
    const int*   toks   = (const int*)d_in[4];
    const unsigned char* mraw = (const unsigned char*)d_in[5];
    const float* headW  = (const float*)d_in[6];
    const float* headB  = (const float*)d_in[7];
    const float* t0proj = (const float*)d_in[8];
    const float* t0out  = (const float*)d_in[9];
    const float* t1proj = (const float*)d_in[10];
    const float* t1out  = (const float*)d_in[11];

    char* ws = (char*)d_ws;
    unsigned short* emb_bf   = (unsigned short*)(ws + 0);          //  4,194,304
    unsigned short* headW_bf = (unsigned short*)(ws + 4194304);    //  8,196,096
    unsigned short* t0out_bf = (unsigned short*)(ws + 12390400);   //  8,192,000
    unsigned short* t1out_bf = (unsigned short*)(ws + 20582400);   //  3,840,000
    unsigned short* projcat  = (unsigned short*)(ws + 24422400);   //    655,360
    float*          h01p     = (float*)(ws + 25077760);            // 10,485,760 (4 slices)
    unsigned short* h0_bf    = (unsigned short*)(ws + 35563520);   //  1,048,576
    unsigned short* h1_bf    = (unsigned short*)(ws + 36612096);   //    262,144
    int*   tgt32  = (int*)(ws + 36874240);
    int*   mask32 = (int*)(ws + 36882432);
    float* seH_p  = (float*)(ws + 36890624);   //  16*2048*4 =   131,072
    float* se0_p  = (float*)(ws + 37152768);   //  63*2048*4 =   516,096
    float* se1_p  = (float*)(ws + 38176768);   //  30*2048*4 =   245,760
    float* tgtH   = (float*)(ws + 40126464);
    float* c0     = (float*)(ws + 40134656);
    float* c1     = (float*)(ws + 40142848);
    float* tg0    = (float*)(ws + 40151040);
    float* tg1    = (float*)(ws + 40159232);
    float* lossPart = (float*)(ws + 40167424); // 64*4

    // weight convert + dtype preprocess (block 2048)
    cvt_all_kernel<<<2049, 256, 0, stream>>>(headW, headW_bf, t0out, t0out_bf,
                                             t1out, t1out_bf, t0proj, projcat,
                                             t1proj, projcat + 262144,
                                             traw, mraw, tgt32, mask32);
    gather_cvt_kernel<<<N_ROWS, 256, 0, stream>>>(lhs, cls, bids, toks, mask32, emb_bf);

    // proj GEMM: h01 = emb @ [t0proj;t1proj]^T  (C=320, split-K z=4 x kLen=256)
    gemm_pipe_kernel<2><<<dim3(16, 3, 4), 256, 0, stream>>>(
        emb_bf, 1024, projcat, 320, h01p, 256);
    cvt_h01_kernel<<<2560, 256, 0, stream>>>(h01p, h0_bf, h1_bf);

    // merged head (256 blocks, NT=16) + tail0 (1008 blocks, NT=4)
    gemmHT_kernel<128, 256><<<1264, 512, 0, stream>>>(
        emb_bf, 1024, headW_bf, 4002, headB, seH_p, 16, 256,
        h0_bf, 256, t0out_bf, 16000, se0_p, 4,
        c0, c1);
    // tail1 specialist: CT=8, grid (16,30)=480 blocks, 2 blocks/CU
    tail1_kernel<8><<<dim3(16, 30), 512, 0, stream>>>(
        h1_bf, t1out_bf, se1_p, 30000);

    dot_kernel<<<512, 256, 0, stream>>>(emb_bf, headW_bf, headB, h0_bf, t0out_bf,
                                        h1_bf, t1out_bf, tgt32,
                                        tgtH, tg0, tg1);
    rowfinal_kernel<<<64, 256, 0, stream>>>(
        seH_p, se0_p, se1_p, tgtH, tg0, tg1, c0, c1, tgt32,
        (float*)d_out, lossPart);
    finalize2_kernel<<<1, 64, 0, stream>>>(lossPart, (float*)d_out);
}

// Round 13
// 122.172 us; speedup vs baseline: 1.3265x; 1.3265x over previous
//
#include <hip/hip_runtime.h>
#include <cstdint>
#include <cstddef>

#define N_ROWS 2048
#define D_DIM  1024

typedef __bf16 bf16x8 __attribute__((ext_vector_type(8)));
typedef float  f32x4  __attribute__((ext_vector_type(4)));

__device__ __forceinline__ unsigned short f2bf(float f) {
    unsigned int u = __float_as_uint(f);
    unsigned int r = (u + 0x7fffu + ((u >> 16) & 1u)) >> 16;   // RNE
    return (unsigned short)r;
}
__device__ __forceinline__ float bf2f(unsigned short u) {
    return __uint_as_float(((unsigned int)u) << 16);
}
__device__ __forceinline__ void gload_lds16(const void* g, void* lds) {
    __builtin_amdgcn_global_load_lds(
        (const __attribute__((address_space(1))) unsigned int*)g,
        (__attribute__((address_space(3))) unsigned int*)lds, 16, 0, 0);
}

template<int N> __device__ __forceinline__ void wait_vmcnt();
template<> __device__ __forceinline__ void wait_vmcnt<0>() { asm volatile("s_waitcnt vmcnt(0)" ::: "memory"); }
template<> __device__ __forceinline__ void wait_vmcnt<2>() { asm volatile("s_waitcnt vmcnt(2)" ::: "memory"); }
template<> __device__ __forceinline__ void wait_vmcnt<4>() { asm volatile("s_waitcnt vmcnt(4)" ::: "memory"); }
template<> __device__ __forceinline__ void wait_vmcnt<6>() { asm volatile("s_waitcnt vmcnt(6)" ::: "memory"); }
template<> __device__ __forceinline__ void wait_vmcnt<8>() { asm volatile("s_waitcnt vmcnt(8)" ::: "memory"); }

// ---------------------------------------------------------------------------
// fused fp32->bf16 convert of all five weight tensors (blocks 0..2047)
// + dtype sniff / normalize of targets & mask (block 2048)
// ---------------------------------------------------------------------------
__global__ __launch_bounds__(256) void cvt_all_kernel(
    const float* __restrict__ s0, unsigned short* __restrict__ d0,  // headW  4002*1024
    const float* __restrict__ s1, unsigned short* __restrict__ d1,  // t0out 16000*256
    const float* __restrict__ s2, unsigned short* __restrict__ d2,  // t1out 30000*64
    const float* __restrict__ s3, unsigned short* __restrict__ d3,  // t0proj  256*1024
    const float* __restrict__ s4, unsigned short* __restrict__ d4,  // t1proj   64*1024
    const unsigned char* __restrict__ traw,
    const unsigned char* __restrict__ mraw,
    int* __restrict__ tgt32, int* __restrict__ mask32)
{
    const int tid = threadIdx.x;
    if (blockIdx.x == 2048) {
        __shared__ int fFloat, fByte, fOdd;
        if (tid == 0) { fFloat = 0; fByte = 0; fOdd = 0; }
        __syncthreads();
        const unsigned int* mw = (const unsigned int*)mraw;
        for (int i = tid; i < 512; i += 256) {
            unsigned int w = mw[i];
            if (w == 0x3f800000u) atomicOr(&fFloat, 1);
            if (w & 0xFFFFFF00u)  atomicOr(&fByte, 1);
        }
        const unsigned int* tw = (const unsigned int*)traw;
        for (int i = tid; i < N_ROWS; i += 256) {
            if ((i & 1) && tw[i] != 0u) atomicOr(&fOdd, 1);
        }
        __syncthreads();
        const int mlayout = fFloat ? 2 : (fByte ? 1 : 0);
        const int tis64   = fOdd ? 0 : 1;
        for (int i = tid; i < N_ROWS; i += 256) {
            long long t = tis64 ? ((const long long*)traw)[i]
                                : (long long)((const int*)traw)[i];
            tgt32[i] = (int)t;
            int m;
            if (mlayout == 1) m = (mraw[i] != 0);
            else              m = (((const unsigned int*)mraw)[i] != 0u);
            mask32[i] = m;
        }
        return;
    }
    const int total = 2610432;  // vec4 units
    for (int i = blockIdx.x * 256 + tid; i < total; i += 2048 * 256) {
        const float* s; unsigned short* d; int off;
        if (i < 1024512)      { s = s0; d = d0; off = i; }
        else if (i < 2048512) { s = s1; d = d1; off = i - 1024512; }
        else if (i < 2528512) { s = s2; d = d2; off = i - 2048512; }
        else if (i < 2594048) { s = s3; d = d3; off = i - 2528512; }
        else                  { s = s4; d = d4; off = i - 2594048; }
        float4 v = ((const float4*)s)[off];
        ushort4 o;
        o.x = f2bf(v.x); o.y = f2bf(v.y); o.z = f2bf(v.z); o.w = f2bf(v.w);
        ((ushort4*)d)[off] = o;
    }
}

// ---------------------------------------------------------------------------
// gather + fp32->bf16: emb[n] = replace ? cls[b] : lhs[b,tok]
// ---------------------------------------------------------------------------
__global__ __launch_bounds__(256) void gather_cvt_kernel(
    const float* __restrict__ lhs, const float* __restrict__ cls,
    const int* __restrict__ bids, const int* __restrict__ toks,
    const int* __restrict__ mask32, unsigned short* __restrict__ emb)
{
    const int n = blockIdx.x;
    const int b = bids[n];
    const int tok = toks[n];
    const float* src = mask32[n] ? (cls + (size_t)b * D_DIM)
                                 : (lhs + ((size_t)b * 512 + (size_t)tok) * D_DIM);
    float4 v = ((const float4*)src)[threadIdx.x];
    ushort4 o;
    o.x = f2bf(v.x); o.y = f2bf(v.y); o.z = f2bf(v.z); o.w = f2bf(v.w);
    ((ushort4*)(emb + (size_t)n * D_DIM))[threadIdx.x] = o;
}

// sum 4 split-K partials, split h01 [2048][320] -> h0 bf16 [2048][256], h1 [2048][64]
__global__ __launch_bounds__(256) void cvt_h01_kernel(
    const float* __restrict__ h01p, unsigned short* __restrict__ h0,
    unsigned short* __restrict__ h1)
{
    const int idx = blockIdx.x * 256 + threadIdx.x;
    if (idx >= 2048 * 320) return;
    const float v = h01p[idx] + h01p[655360 + idx] + h01p[1310720 + idx]
                  + h01p[1966080 + idx];
    const int r = idx / 320;
    const int c = idx - r * 320;
    const unsigned short b = f2bf(v);
    if (c < 256) h0[r * 256 + c] = b;
    else         h1[r * 64 + (c - 256)] = b;
}

// ---------------------------------------------------------------------------
// 8-wave big-tile GEMM, 3-deep LDS ring, ONE barrier per K-tile (R11-proven).
// Fused per-row sum(exp(logit+bias)) -> part[by*2048+row].
// Optional head cluster-logit capture (block-uniform: only cB=3840 block).
// ---------------------------------------------------------------------------
template<int BM, int BN>
__global__ __launch_bounds__(512, 2) void gemm8w_kernel(
    const unsigned short* __restrict__ A, int K,
    const unsigned short* __restrict__ W, int C,
    const float* __restrict__ bias,
    float* __restrict__ part, int NT,
    float* __restrict__ c0cap, float* __restrict__ c1cap)
{
    constexpr int WM = BM / 2, WN = BN / 4;
    constexpr int MF = WM / 16, NF = WN / 16;
    constexpr int NA = BM / 64, NB = BN / 64;
    constexpr int L  = NA + NB;
    constexpr int ABYTES   = BM * 128;
    constexpr int BUFBYTES = (BM + BN) * 128;
    __shared__ char lds[3 * BUFBYTES];

    const int gx = gridDim.x, gy = gridDim.y;
    const int nwg = gx * gy;
    const int lid = blockIdx.x + gx * blockIdx.y;
    const int xcd = lid & 7, idx8 = lid >> 3;
    const int qq = nwg >> 3, rr = nwg & 7;
    const int wg = (xcd < rr ? xcd * (qq + 1) : rr * (qq + 1) + (xcd - rr) * qq) + idx8;
    const int bx = wg % gx;
    const int by = wg / gx;

    const int tid = threadIdx.x;
    const int w = tid >> 6, l = tid & 63;
    const int wr = w >> 2, wc = w & 3;
    const int q16 = l >> 4, r16 = l & 15;
    const int rowA0 = bx * BM;
    const int cB = by * BN;

    const int srow = tid >> 3;
    const int sp   = (tid & 7) ^ (srow & 7);
    const unsigned short* aSrc[NA];
    const unsigned short* bSrc[NB];
    #pragma unroll
    for (int c = 0; c < NA; ++c)
        aSrc[c] = A + (size_t)(rowA0 + c * 64 + srow) * K + sp * 8;
    #pragma unroll
    for (int c = 0; c < NB; ++c) {
        int rbl = cB + c * 64 + srow;
        if (rbl >= C) rbl = C - 1;
        bSrc[c] = W + (size_t)rbl * K + sp * 8;
    }

    auto stage = [&](int kt, int buf) {
        char* base = lds + buf * BUFBYTES;
        #pragma unroll
        for (int c = 0; c < NA; ++c)
            gload_lds16(aSrc[c] + kt * 64, base + c * 8192 + (w << 10));
        #pragma unroll
        for (int c = 0; c < NB; ++c)
            gload_lds16(bSrc[c] + kt * 64, base + ABYTES + c * 8192 + (w << 10));
    };

    f32x4 acc[MF][NF];
    #pragma unroll
    for (int m = 0; m < MF; ++m)
        #pragma unroll
        for (int n = 0; n < NF; ++n) acc[m][n] = (f32x4){0.f, 0.f, 0.f, 0.f};

    stage(0, 0);
    if (NT > 1) stage(1, 1);

    for (int kt = 0; kt < NT; ++kt) {
        const int buf = kt % 3;
        if (kt + 1 < NT) wait_vmcnt<L>(); else wait_vmcnt<0>();
        __builtin_amdgcn_s_barrier();
        __builtin_amdgcn_sched_barrier(0);
        if (kt + 2 < NT) stage(kt + 2, (kt + 2) % 3);
        __builtin_amdgcn_sched_barrier(0);

        const char* Ab = lds + buf * BUFBYTES;
        const char* Bb = Ab + ABYTES;
        #pragma unroll
        for (int ks = 0; ks < 2; ++ks) {
            const int xs = ((ks * 4 + q16) ^ (l & 7)) << 4;
            bf16x8 af[MF], bv[NF];
            #pragma unroll
            for (int m = 0; m < MF; ++m)
                af[m] = *reinterpret_cast<const bf16x8*>(
                    Ab + (wr * WM + m * 16 + r16) * 128 + xs);
            #pragma unroll
            for (int n = 0; n < NF; ++n)
                bv[n] = *reinterpret_cast<const bf16x8*>(
                    Bb + (wc * WN + n * 16 + r16) * 128 + xs);
            __builtin_amdgcn_s_setprio(1);
            #pragma unroll
            for (int m = 0; m < MF; ++m)
                #pragma unroll
                for (int n = 0; n < NF; ++n)
                    acc[m][n] = __builtin_amdgcn_mfma_f32_16x16x32_bf16(
                        af[m], bv[n], acc[m][n], 0, 0, 0);
            __builtin_amdgcn_s_setprio(0);
        }
    }

    float bj[NF]; bool vj[NF];
    #pragma unroll
    for (int n = 0; n < NF; ++n) {
        const int c = cB + wc * WN + n * 16 + r16;
        vj[n] = (c < C);
        bj[n] = (vj[n] && bias) ? bias[c] : 0.f;
    }

    // head cluster-logit capture (block-uniform: only the cB=3840 block)
    if (c0cap != nullptr && cB + BN > 4000) {
        #pragma unroll
        for (int n = 0; n < NF; ++n) {
            const int c = cB + wc * WN + n * 16 + r16;
            if (c == 4000 || c == 4001) {
                float* dst = (c == 4000) ? c0cap : c1cap;
                #pragma unroll
                for (int m = 0; m < MF; ++m)
                    #pragma unroll
                    for (int r = 0; r < 4; ++r) {
                        const int row = rowA0 + wr * WM + m * 16 + q16 * 4 + r;
                        dst[row] = acc[m][n][r] + bj[n];
                    }
            }
        }
    }

    __syncthreads();
    float* pl = (float*)lds;
    #pragma unroll
    for (int m = 0; m < MF; ++m)
        #pragma unroll
        for (int r = 0; r < 4; ++r) {
            float s = 0.f;
            #pragma unroll
            for (int n = 0; n < NF; ++n)
                if (vj[n]) s += __expf(acc[m][n][r] + bj[n]);
            s += __shfl_xor(s, 1); s += __shfl_xor(s, 2);
            s += __shfl_xor(s, 4); s += __shfl_xor(s, 8);
            if (r16 == 0)
                pl[wc * BM + wr * WM + m * 16 + q16 * 4 + r] = s;
        }
    __syncthreads();
    if (tid < BM)
        part[(size_t)by * N_ROWS + rowA0 + tid] =
            pl[tid] + pl[BM + tid] + pl[2 * BM + tid] + pl[3 * BM + tid];
}

// ---------------------------------------------------------------------------
// tail1 specialist: K=64 one tile -> pipeline along COLUMNS. A staged once,
// A-frags in registers; W streams through a 3-buf LDS ring (single barrier,
// counted vmcnt(2)). LDS 64KB -> 2 blocks/CU for inter-block overlap.
// ---------------------------------------------------------------------------
template<int CT>
__global__ __launch_bounds__(512, 4) void tail1_kernel(
    const unsigned short* __restrict__ A,   // [2048][64]
    const unsigned short* __restrict__ W,   // [C][64]
    float* __restrict__ part, int C)
{
    __shared__ char lds[65536];   // A @0 (16KB), W ring @16384 + buf*16384

    const int gx = gridDim.x, gy = gridDim.y;
    const int nwg = gx * gy;
    const int lid = blockIdx.x + gx * blockIdx.y;
    const int xcd = lid & 7, idx8 = lid >> 3;
    const int qq = nwg >> 3, rr = nwg & 7;
    const int wg = (xcd < rr ? xcd * (qq + 1) : rr * (qq + 1) + (xcd - rr) * qq) + idx8;
    const int bx = wg % gx;
    const int by = wg / gx;

    const int tid = threadIdx.x;
    const int w = tid >> 6, l = tid & 63;
    const int wr = w >> 2, wc = w & 3;      // WM=64 (MF=4), WN=32 (NF=2)
    const int q16 = l >> 4, r16 = l & 15;
    const int rowA0 = bx * 128;
    const int cB0 = by * (CT * 128);

    const int srow = tid >> 3;
    const int sp   = (tid & 7) ^ (srow & 7);

    #pragma unroll
    for (int c = 0; c < 2; ++c)
        gload_lds16(A + (size_t)(rowA0 + c * 64 + srow) * 64 + sp * 8,
                    lds + c * 8192 + (w << 10));

    auto stageW = [&](int ct, int buf) {
        char* base = lds + 16384 + buf * 16384;
        #pragma unroll
        for (int c = 0; c < 2; ++c) {
            int rw = cB0 + ct * 128 + c * 64 + srow;
            if (rw >= C) rw = C - 1;
            gload_lds16(W + (size_t)rw * 64 + sp * 8, base + c * 8192 + (w << 10));
        }
    };
    stageW(0, 0);
    if (CT > 1) stageW(1, 1);

    wait_vmcnt<4>();                 // own A loads (oldest 2) landed
    __builtin_amdgcn_s_barrier();    // -> all waves' A writes landed

    bf16x8 areg[2][4];
    #pragma unroll
    for (int ks = 0; ks < 2; ++ks)
        #pragma unroll
        for (int m = 0; m < 4; ++m) {
            const int row = wr * 64 + m * 16 + r16;
            const int xs = ((ks * 4 + q16) ^ (l & 7)) << 4;
            areg[ks][m] = *reinterpret_cast<const bf16x8*>(lds + row * 128 + xs);
        }

    float esum[4][4];
    #pragma unroll
    for (int m = 0; m < 4; ++m)
        #pragma unroll
        for (int r = 0; r < 4; ++r) esum[m][r] = 0.f;

    for (int ct = 0; ct < CT; ++ct) {
        const int buf = ct % 3;
        if (ct + 1 < CT) wait_vmcnt<2>(); else wait_vmcnt<0>();
        __builtin_amdgcn_s_barrier();
        __builtin_amdgcn_sched_barrier(0);
        if (ct + 2 < CT) stageW(ct + 2, (ct + 2) % 3);
        __builtin_amdgcn_sched_barrier(0);

        const char* Bb = lds + 16384 + buf * 16384;
        bf16x8 wreg[2][2];
        #pragma unroll
        for (int ks = 0; ks < 2; ++ks)
            #pragma unroll
            for (int n = 0; n < 2; ++n) {
                const int row = wc * 32 + n * 16 + r16;
                const int xs = ((ks * 4 + q16) ^ (l & 7)) << 4;
                wreg[ks][n] = *reinterpret_cast<const bf16x8*>(Bb + row * 128 + xs);
            }

        f32x4 acc[4][2];
        #pragma unroll
        for (int m = 0; m < 4; ++m)
            #pragma unroll
            for (int n = 0; n < 2; ++n) acc[m][n] = (f32x4){0.f, 0.f, 0.f, 0.f};

        __builtin_amdgcn_s_setprio(1);
        #pragma unroll
        for (int ks = 0; ks < 2; ++ks)
            #pragma unroll
            for (int m = 0; m < 4; ++m)
                #pragma unroll
                for (int n = 0; n < 2; ++n)
                    acc[m][n] = __builtin_amdgcn_mfma_f32_16x16x32_bf16(
                        areg[ks][m], wreg[ks][n], acc[m][n], 0, 0, 0);
        __builtin_amdgcn_s_setprio(0);

        bool vj[2];
        #pragma unroll
        for (int n = 0; n < 2; ++n)
            vj[n] = (cB0 + ct * 128 + wc * 32 + n * 16 + r16) < C;
        #pragma unroll
        for (int m = 0; m < 4; ++m)
            #pragma unroll
            for (int r = 0; r < 4; ++r) {
                float s = 0.f;
                #pragma unroll
                for (int n = 0; n < 2; ++n)
                    if (vj[n]) s += __expf(acc[m][n][r]);
                esum[m][r] += s;
            }
    }

    __syncthreads();
    float* pl = (float*)lds;
    #pragma unroll
    for (int m = 0; m < 4; ++m)
        #pragma unroll
        for (int r = 0; r < 4; ++r) {
            float v = esum[m][r];
            v += __shfl_xor(v, 1); v += __shfl_xor(v, 2);
            v += __shfl_xor(v, 4); v += __shfl_xor(v, 8);
            if (r16 == 0)
                pl[wc * 128 + wr * 64 + m * 16 + q16 * 4 + r] = v;
        }
    __syncthreads();
    if (tid < 128)
        part[(size_t)by * N_ROWS + rowA0 + tid] =
            pl[tid] + pl[128 + tid] + pl[256 + tid] + pl[384 + tid];
}

// ---------------------------------------------------------------------------
// proj GEMM (128-tile ring pipeline, split-K plain stores) — unchanged (proven)
// ---------------------------------------------------------------------------
template<int MODE>
__global__ __launch_bounds__(256) void gemm_pipe_kernel(
    const unsigned short* __restrict__ A, int K,
    const unsigned short* __restrict__ W, int C,
    float* __restrict__ outF, int kLen)
{
    __shared__ char lds[49152];

    const int gx = gridDim.x, gy = gridDim.y;
    const int nwg = gx * gy * gridDim.z;
    const int lid = blockIdx.x + gx * (blockIdx.y + gy * blockIdx.z);
    const int xcd = lid & 7, idx8 = lid >> 3;
    const int qq = nwg >> 3, rr = nwg & 7;
    const int wg = (xcd < rr ? xcd * (qq + 1) : rr * (qq + 1) + (xcd - rr) * qq) + idx8;
    const int bx = wg % gx;
    const int t1 = wg / gx;
    const int by = t1 % gy;
    const int bz = t1 / gy;

    const int tid = threadIdx.x;
    const int w = tid >> 6, l = tid & 63;
    const int wr = w >> 1, wc = w & 1;
    const int q16 = l >> 4, r16 = l & 15;
    const int rowA0 = bx << 7;
    const int kBeg = bz * kLen;

    const int sRl = (w << 5) + (l >> 2);
    const int sS  = l & 3;
    const int nt  = kLen >> 5;

    const unsigned short* aB[2];
    const unsigned short* wB[2];
    #pragma unroll
    for (int it = 0; it < 2; ++it) {
        const int R  = sRl + (it << 4);
        const int Sp = sS ^ ((R >> 1) & 3);
        aB[it] = A + (size_t)(rowA0 + R) * K + kBeg + Sp * 8;
        int Rw = (by << 7) + R; if (Rw >= C) Rw = C - 1;
        wB[it] = W + (size_t)Rw * K + kBeg + Sp * 8;
    }

    auto stage = [&](int ksv, int buf) {
        char* Ab = lds + buf * 16384;
        char* Wb = Ab + 8192;
        const int ko = ksv << 5;
        #pragma unroll
        for (int it = 0; it < 2; ++it) {
            gload_lds16(aB[it] + ko, Ab + (w << 11) + (it << 10));
            gload_lds16(wB[it] + ko, Wb + (w << 11) + (it << 10));
        }
    };

    f32x4 acc[4][4];
    #pragma unroll
    for (int m = 0; m < 4; ++m)
        #pragma unroll
        for (int n = 0; n < 4; ++n) acc[m][n] = (f32x4){0.f, 0.f, 0.f, 0.f};

    stage(0, 0); stage(1, 1); stage(2, 2);

    for (int s = 0; s < nt; ++s) {
        const int rem = nt - 1 - s;
        if (rem >= 2)      wait_vmcnt<8>();
        else if (rem == 1) wait_vmcnt<4>();
        else               wait_vmcnt<0>();
        __builtin_amdgcn_s_barrier();
        __builtin_amdgcn_sched_barrier(0);

        char* Ab = lds + (s % 3) * 16384;
        char* Wb = Ab + 8192;
        bf16x8 af[4], bfr[4];
        #pragma unroll
        for (int m = 0; m < 4; ++m) {
            const int row = (wr << 6) + (m << 4) + r16;
            af[m] = *reinterpret_cast<const bf16x8*>(
                Ab + row * 64 + ((q16 ^ ((row >> 1) & 3)) << 4));
        }
        #pragma unroll
        for (int n = 0; n < 4; ++n) {
            const int row = (wc << 6) + (n << 4) + r16;
            bfr[n] = *reinterpret_cast<const bf16x8*>(
                Wb + row * 64 + ((q16 ^ ((row >> 1) & 3)) << 4));
        }
        __builtin_amdgcn_sched_barrier(0);
        __builtin_amdgcn_s_barrier();

        if (s + 3 < nt) stage(s + 3, s % 3);

        __builtin_amdgcn_s_setprio(1);
        #pragma unroll
        for (int m = 0; m < 4; ++m)
            #pragma unroll
            for (int n = 0; n < 4; ++n)
                acc[m][n] = __builtin_amdgcn_mfma_f32_16x16x32_bf16(
                    af[m], bfr[n], acc[m][n], 0, 0, 0);
        __builtin_amdgcn_s_setprio(0);
    }

    float* o = outF + (size_t)bz * ((size_t)N_ROWS * C);
    #pragma unroll
    for (int n = 0; n < 4; ++n) {
        const int c = (by << 7) + (wc << 6) + (n << 4) + r16;
        if (c < C) {
            #pragma unroll
            for (int m = 0; m < 4; ++m)
                #pragma unroll
                for (int r = 0; r < 4; ++r) {
                    const int row = rowA0 + (wr << 6) + (m << 4) + (q16 << 2) + r;
                    o[(size_t)row * C + c] = acc[m][n][r];
                }
        }
    }
}

// ---------------------------------------------------------------------------
// slim per-row target-logit dot (one wave per row; single dot per row)
// ---------------------------------------------------------------------------
__global__ __launch_bounds__(256) void dot_kernel(
    const unsigned short* __restrict__ emb,
    const unsigned short* __restrict__ headW,
    const float* __restrict__ headB,
    const unsigned short* __restrict__ h0,
    const unsigned short* __restrict__ t0out,
    const unsigned short* __restrict__ h1,
    const unsigned short* __restrict__ t1out,
    const int* __restrict__ tgt32,
    float* __restrict__ tgtH, float* __restrict__ tg0, float* __restrict__ tg1)
{
    const int n = blockIdx.x * 4 + (threadIdx.x >> 6);
    const int l = threadIdx.x & 63;
    const int t = tgt32[n];

    float sv = 0.f;
    if (t < 4000) {
        const unsigned short* e  = emb + (size_t)n * 1024;
        const unsigned short* wt = headW + (size_t)t * 1024;
        for (int i = l; i < 1024; i += 64) sv += bf2f(e[i]) * bf2f(wt[i]);
    } else if (t < 20000) {
        const unsigned short* h  = h0 + (size_t)n * 256;
        const unsigned short* ww = t0out + (size_t)(t - 4000) * 256;
        for (int i = l; i < 256; i += 64) sv += bf2f(h[i]) * bf2f(ww[i]);
    } else {
        const unsigned short* h  = h1 + (size_t)n * 64;
        const unsigned short* ww = t1out + (size_t)(t - 20000) * 64;
        sv = bf2f(h[l]) * bf2f(ww[l]);
    }
    #pragma unroll
    for (int msk = 1; msk < 64; msk <<= 1) sv += __shfl_xor(sv, msk);
    if (l == 0) {
        if (t < 4000)       tgtH[n] = sv + headB[t];
        else if (t < 20000) tg0[n]  = sv;
        else                tg1[n]  = sv;
    }
}

// ---------------------------------------------------------------------------
// rowfinal: per-row reduce of the 3 partial arrays + log-softmax combine.
// grid 64 x 256 threads: 32 rows/block, 8 lanes/row. Also block loss partial.
// ---------------------------------------------------------------------------
__global__ __launch_bounds__(256) void rowfinal_kernel(
    const float* __restrict__ pH, const float* __restrict__ p0,
    const float* __restrict__ p1,
    const float* __restrict__ tgtH, const float* __restrict__ tg0,
    const float* __restrict__ tg1,
    const float* __restrict__ c0, const float* __restrict__ c1,
    const int* __restrict__ tgt32,
    float* __restrict__ out, float* __restrict__ lossPart)
{
    const int tid = threadIdx.x;
    const int rloc = tid >> 3, g = tid & 7;
    const int row = blockIdx.x * 32 + rloc;

    float sH = 0.f, s0 = 0.f, s1 = 0.f;
    for (int i = g; i < 16; i += 8) sH += pH[(size_t)i * N_ROWS + row];
    for (int i = g; i < 63; i += 8) s0 += p0[(size_t)i * N_ROWS + row];
    for (int i = g; i < 30; i += 8) s1 += p1[(size_t)i * N_ROWS + row];
    #pragma unroll
    for (int msk = 1; msk < 8; msk <<= 1) {
        sH += __shfl_xor(sH, msk);
        s0 += __shfl_xor(s0, msk);
        s1 += __shfl_xor(s1, msk);
    }
    __shared__ float sO[32];
    if (g == 0) {
        const int t = tgt32[row];
        const float lseH = logf(sH);
        float o;
        if (t < 4000)        o = tgtH[row] - lseH;
        else if (t < 20000)  o = (c0[row] - lseH) + tg0[row] - logf(s0);
        else                 o = (c1[row] - lseH) + tg1[row] - logf(s1);
        out[row] = o;
        sO[rloc] = o;
    }
    __syncthreads();
    if (tid < 64) {
        float v = (tid < 32) ? sO[tid] : 0.f;
        #pragma unroll
        for (int msk = 1; msk < 64; msk <<= 1) v += __shfl_xor(v, msk);
        if (tid == 0) lossPart[blockIdx.x] = v;
    }
}

// ---------------------------------------------------------------------------
__global__ __launch_bounds__(64) void finalize2_kernel(
    const float* __restrict__ lossPart, float* __restrict__ out)
{
    float v = lossPart[threadIdx.x];
    #pragma unroll
    for (int msk = 1; msk < 64; msk <<= 1) v += __shfl_xor(v, msk);
    if (threadIdx.x == 0) out[N_ROWS] = -v / (float)N_ROWS;
}

// ---------------------------------------------------------------------------
extern "C" void kernel_launch(void* const* d_in, const int* in_sizes, int n_in,
                              void* d_out, int out_size, void* d_ws, size_t ws_size,
                              hipStream_t stream)
{
    const unsigned char* traw = (const unsigned char*)d_in[0];
    const float* lhs    = (const float*)d_in[1];
    const float* cls    = (const float*)d_in[2];
    const int*   bids   = (const int*)d_in[3];
    const int*   toks   = (const int*)d_in[4];
    const unsigned char* mraw = (const unsigned char*)d_in[5];
    const float* headW  = (const float*)d_in[6];
    const float* headB  = (const float*)d_in[7];
    const float* t0proj = (const float*)d_in[8];
    const float* t0out  = (const float*)d_in[9];
    const float* t1proj = (const float*)d_in[10];
    const float* t1out  = (const float*)d_in[11];

    char* ws = (char*)d_ws;
    unsigned short* emb_bf   = (unsigned short*)(ws + 0);          //  4,194,304
    unsigned short* headW_bf = (unsigned short*)(ws + 4194304);    //  8,196,096
    unsigned short* t0out_bf = (unsigned short*)(ws + 12390400);   //  8,192,000
    unsigned short* t1out_bf = (unsigned short*)(ws + 20582400);   //  3,840,000
    unsigned short* projcat  = (unsigned short*)(ws + 24422400);   //    655,360
    float*          h01p     = (float*)(ws + 25077760);            // 10,485,760 (4 slices)
    unsigned short* h0_bf    = (unsigned short*)(ws + 35563520);   //  1,048,576
    unsigned short* h1_bf    = (unsigned short*)(ws + 36612096);   //    262,144
    int*   tgt32  = (int*)(ws + 36874240);
    int*   mask32 = (int*)(ws + 36882432);
    float* seH_p  = (float*)(ws + 36890624);   //  16*2048*4 =   131,072
    float* se0_p  = (float*)(ws + 37152768);   //  63*2048*4 =   516,096
    float* se1_p  = (float*)(ws + 38176768);   //  30*2048*4 =   245,760
    float* tgtH   = (float*)(ws + 40126464);
    float* c0     = (float*)(ws + 40134656);
    float* c1     = (float*)(ws + 40142848);
    float* tg0    = (float*)(ws + 40151040);
    float* tg1    = (float*)(ws + 40159232);
    float* lossPart = (float*)(ws + 40167424); // 64*4

    // weight convert + dtype preprocess (block 2048)
    cvt_all_kernel<<<2049, 256, 0, stream>>>(headW, headW_bf, t0out, t0out_bf,
                                             t1out, t1out_bf, t0proj, projcat,
                                             t1proj, projcat + 262144,
                                             traw, mraw, tgt32, mask32);
    gather_cvt_kernel<<<N_ROWS, 256, 0, stream>>>(lhs, cls, bids, toks, mask32, emb_bf);

    // proj GEMM: h01 = emb @ [t0proj;t1proj]^T  (C=320, split-K z=4 x kLen=256)
    gemm_pipe_kernel<2><<<dim3(16, 3, 4), 256, 0, stream>>>(
        emb_bf, 1024, projcat, 320, h01p, 256);
    cvt_h01_kernel<<<2560, 256, 0, stream>>>(h01p, h0_bf, h1_bf);

    // head: BM=128 BN=256, grid (16,16)=256 blocks, NT=16 (+ c0/c1 capture)
    gemm8w_kernel<128, 256><<<dim3(16, 16), 512, 0, stream>>>(
        emb_bf, 1024, headW_bf, 4002, headB, seH_p, 16, c0, c1);
    // tail0: BM=128 BN=256, grid (16,63)=1008 blocks, NT=4
    gemm8w_kernel<128, 256><<<dim3(16, 63), 512, 0, stream>>>(
        h0_bf, 256, t0out_bf, 16000, nullptr, se0_p, 4, nullptr, nullptr);
    // tail1 specialist: CT=8, grid (16,30)=480 blocks, 2 blocks/CU
    tail1_kernel<8><<<dim3(16, 30), 512, 0, stream>>>(
        h1_bf, t1out_bf, se1_p, 30000);

    dot_kernel<<<512, 256, 0, stream>>>(emb_bf, headW_bf, headB, h0_bf, t0out_bf,
                                        h1_bf, t1out_bf, tgt32,
                                        tgtH, tg0, tg1);
    rowfinal_kernel<<<64, 256, 0, stream>>>(
        seH_p, se0_p, se1_p, tgtH, tg0, tg1, c0, c1, tgt32,
        (float*)d_out, lossPart);
    finalize2_kernel<<<1, 64, 0, stream>>>(lossPart, (float*)d_out);
}

// Round 14
// 101.610 us; speedup vs baseline: 1.5950x; 1.2024x over previous
//
#include <hip/hip_runtime.h>
#include <cstdint>
#include <cstddef>

#define N_ROWS 2048
#define D_DIM  1024

typedef __bf16 bf16x8 __attribute__((ext_vector_type(8)));
typedef float  f32x4  __attribute__((ext_vector_type(4)));

__device__ __forceinline__ unsigned short f2bf(float f) {
    unsigned int u = __float_as_uint(f);
    unsigned int r = (u + 0x7fffu + ((u >> 16) & 1u)) >> 16;   // RNE
    return (unsigned short)r;
}
__device__ __forceinline__ float bf2f(unsigned short u) {
    return __uint_as_float(((unsigned int)u) << 16);
}
__device__ __forceinline__ void gload_lds16(const void* g, void* lds) {
    __builtin_amdgcn_global_load_lds(
        (const __attribute__((address_space(1))) unsigned int*)g,
        (__attribute__((address_space(3))) unsigned int*)lds, 16, 0, 0);
}

template<int N> __device__ __forceinline__ void wait_vmcnt();
template<> __device__ __forceinline__ void wait_vmcnt<0>() { asm volatile("s_waitcnt vmcnt(0)" ::: "memory"); }
template<> __device__ __forceinline__ void wait_vmcnt<2>() { asm volatile("s_waitcnt vmcnt(2)" ::: "memory"); }
template<> __device__ __forceinline__ void wait_vmcnt<4>() { asm volatile("s_waitcnt vmcnt(4)" ::: "memory"); }
template<> __device__ __forceinline__ void wait_vmcnt<6>() { asm volatile("s_waitcnt vmcnt(6)" ::: "memory"); }
template<> __device__ __forceinline__ void wait_vmcnt<8>() { asm volatile("s_waitcnt vmcnt(8)" ::: "memory"); }

// ---------------------------------------------------------------------------
// blocks 0..2047   : fp32->bf16 convert of all five weight tensors
// block 2048       : targets int32/int64 sniff + normalize -> tgt32
// blocks 2049..4096: gather row (b-2049): emb = replace ? cls : lhs, ->bf16.
//                    mask layout self-detected via 2KB scan (L2-hit).
// ---------------------------------------------------------------------------
__global__ __launch_bounds__(256) void cvtgather_kernel(
    const float* __restrict__ s0, unsigned short* __restrict__ d0,  // headW  4002*1024
    const float* __restrict__ s1, unsigned short* __restrict__ d1,  // t0out 16000*256
    const float* __restrict__ s2, unsigned short* __restrict__ d2,  // t1out 30000*64
    const float* __restrict__ s3, unsigned short* __restrict__ d3,  // t0proj  256*1024
    const float* __restrict__ s4, unsigned short* __restrict__ d4,  // t1proj   64*1024
    const unsigned char* __restrict__ traw,
    const unsigned char* __restrict__ mraw,
    int* __restrict__ tgt32,
    const float* __restrict__ lhs, const float* __restrict__ cls,
    const int* __restrict__ bids, const int* __restrict__ toks,
    unsigned short* __restrict__ emb)
{
    const int tid = threadIdx.x;
    const int blk = blockIdx.x;

    if (blk < 2048) {                       // weight convert
        const int total = 2610432;          // vec4 units
        for (int i = blk * 256 + tid; i < total; i += 2048 * 256) {
            const float* s; unsigned short* d; int off;
            if (i < 1024512)      { s = s0; d = d0; off = i; }
            else if (i < 2048512) { s = s1; d = d1; off = i - 1024512; }
            else if (i < 2528512) { s = s2; d = d2; off = i - 2048512; }
            else if (i < 2594048) { s = s3; d = d3; off = i - 2528512; }
            else                  { s = s4; d = d4; off = i - 2594048; }
            float4 v = ((const float4*)s)[off];
            ushort4 o;
            o.x = f2bf(v.x); o.y = f2bf(v.y); o.z = f2bf(v.z); o.w = f2bf(v.w);
            ((ushort4*)d)[off] = o;
        }
        return;
    }

    if (blk == 2048) {                      // targets sniff + normalize
        __shared__ int fOdd;
        if (tid == 0) fOdd = 0;
        __syncthreads();
        const unsigned int* tw = (const unsigned int*)traw;
        for (int i = tid; i < N_ROWS; i += 256)
            if ((i & 1) && tw[i] != 0u) atomicOr(&fOdd, 1);
        __syncthreads();
        const int tis64 = fOdd ? 0 : 1;
        for (int i = tid; i < N_ROWS; i += 256) {
            long long t = tis64 ? ((const long long*)traw)[i]
                                : (long long)((const int*)traw)[i];
            tgt32[i] = (int)t;
        }
        return;
    }

    // gather (self-detecting mask layout)
    __shared__ int fFloat, fByte;
    if (tid == 0) { fFloat = 0; fByte = 0; }
    __syncthreads();
    const unsigned int* mw = (const unsigned int*)mraw;
    for (int i = tid; i < 512; i += 256) {
        unsigned int w2 = mw[i];
        if (w2 == 0x3f800000u) atomicOr(&fFloat, 1);
        if (w2 & 0xFFFFFF00u)  atomicOr(&fByte, 1);
    }
    __syncthreads();
    const int n = blk - 2049;
    int m;
    if (!fFloat && fByte) m = (mraw[n] != 0);
    else                  m = (mw[n] != 0);
    const int b = bids[n];
    const int tok = toks[n];
    const float* src = m ? (cls + (size_t)b * D_DIM)
                         : (lhs + ((size_t)b * 512 + (size_t)tok) * D_DIM);
    float4 v = ((const float4*)src)[tid];
    ushort4 o;
    o.x = f2bf(v.x); o.y = f2bf(v.y); o.z = f2bf(v.z); o.w = f2bf(v.w);
    ((ushort4*)(emb + (size_t)n * D_DIM))[tid] = o;
}

// sum 4 split-K partials, split h01 [2048][320] -> h0 bf16 [2048][256], h1 [2048][64]
__global__ __launch_bounds__(256) void cvt_h01_kernel(
    const float* __restrict__ h01p, unsigned short* __restrict__ h0,
    unsigned short* __restrict__ h1)
{
    const int idx = blockIdx.x * 256 + threadIdx.x;
    if (idx >= 2048 * 320) return;
    const float v = h01p[idx] + h01p[655360 + idx] + h01p[1310720 + idx]
                  + h01p[1966080 + idx];
    const int r = idx / 320;
    const int c = idx - r * 320;
    const unsigned short b = f2bf(v);
    if (c < 256) h0[r * 256 + c] = b;
    else         h1[r * 64 + (c - 256)] = b;
}

// ---------------------------------------------------------------------------
// HEAD: 8-wave <128,256> GEMM, 3-deep LDS ring, ONE barrier per K-tile
// (R11-proven). Fused sum(exp(logit+bias)) -> part; c0/c1 capture
// (block-uniform: only the cB=3840 block).
// ---------------------------------------------------------------------------
template<int BM, int BN>
__global__ __launch_bounds__(512, 2) void gemm8w_kernel(
    const unsigned short* __restrict__ A, int K,
    const unsigned short* __restrict__ W, int C,
    const float* __restrict__ bias,
    float* __restrict__ part, int NT,
    float* __restrict__ c0cap, float* __restrict__ c1cap)
{
    constexpr int WM = BM / 2, WN = BN / 4;
    constexpr int MF = WM / 16, NF = WN / 16;
    constexpr int NA = BM / 64, NB = BN / 64;
    constexpr int L  = NA + NB;
    constexpr int ABYTES   = BM * 128;
    constexpr int BUFBYTES = (BM + BN) * 128;
    __shared__ char lds[3 * BUFBYTES];

    const int gx = gridDim.x, gy = gridDim.y;
    const int nwg = gx * gy;
    const int lid = blockIdx.x + gx * blockIdx.y;
    const int xcd = lid & 7, idx8 = lid >> 3;
    const int qq = nwg >> 3, rr = nwg & 7;
    const int wg = (xcd < rr ? xcd * (qq + 1) : rr * (qq + 1) + (xcd - rr) * qq) + idx8;
    const int bx = wg % gx;
    const int by = wg / gx;

    const int tid = threadIdx.x;
    const int w = tid >> 6, l = tid & 63;
    const int wr = w >> 2, wc = w & 3;
    const int q16 = l >> 4, r16 = l & 15;
    const int rowA0 = bx * BM;
    const int cB = by * BN;

    const int srow = tid >> 3;
    const int sp   = (tid & 7) ^ (srow & 7);
    const unsigned short* aSrc[NA];
    const unsigned short* bSrc[NB];
    #pragma unroll
    for (int c = 0; c < NA; ++c)
        aSrc[c] = A + (size_t)(rowA0 + c * 64 + srow) * K + sp * 8;
    #pragma unroll
    for (int c = 0; c < NB; ++c) {
        int rbl = cB + c * 64 + srow;
        if (rbl >= C) rbl = C - 1;
        bSrc[c] = W + (size_t)rbl * K + sp * 8;
    }

    auto stage = [&](int kt, int buf) {
        char* base = lds + buf * BUFBYTES;
        #pragma unroll
        for (int c = 0; c < NA; ++c)
            gload_lds16(aSrc[c] + kt * 64, base + c * 8192 + (w << 10));
        #pragma unroll
        for (int c = 0; c < NB; ++c)
            gload_lds16(bSrc[c] + kt * 64, base + ABYTES + c * 8192 + (w << 10));
    };

    f32x4 acc[MF][NF];
    #pragma unroll
    for (int m = 0; m < MF; ++m)
        #pragma unroll
        for (int n = 0; n < NF; ++n) acc[m][n] = (f32x4){0.f, 0.f, 0.f, 0.f};

    stage(0, 0);
    if (NT > 1) stage(1, 1);

    for (int kt = 0; kt < NT; ++kt) {
        const int buf = kt % 3;
        if (kt + 1 < NT) wait_vmcnt<L>(); else wait_vmcnt<0>();
        __builtin_amdgcn_s_barrier();
        __builtin_amdgcn_sched_barrier(0);
        if (kt + 2 < NT) stage(kt + 2, (kt + 2) % 3);
        __builtin_amdgcn_sched_barrier(0);

        const char* Ab = lds + buf * BUFBYTES;
        const char* Bb = Ab + ABYTES;
        #pragma unroll
        for (int ks = 0; ks < 2; ++ks) {
            const int xs = ((ks * 4 + q16) ^ (l & 7)) << 4;
            bf16x8 af[MF], bv[NF];
            #pragma unroll
            for (int m = 0; m < MF; ++m)
                af[m] = *reinterpret_cast<const bf16x8*>(
                    Ab + (wr * WM + m * 16 + r16) * 128 + xs);
            #pragma unroll
            for (int n = 0; n < NF; ++n)
                bv[n] = *reinterpret_cast<const bf16x8*>(
                    Bb + (wc * WN + n * 16 + r16) * 128 + xs);
            __builtin_amdgcn_s_setprio(1);
            #pragma unroll
            for (int m = 0; m < MF; ++m)
                #pragma unroll
                for (int n = 0; n < NF; ++n)
                    acc[m][n] = __builtin_amdgcn_mfma_f32_16x16x32_bf16(
                        af[m], bv[n], acc[m][n], 0, 0, 0);
            __builtin_amdgcn_s_setprio(0);
        }
    }

    float bj[NF]; bool vj[NF];
    #pragma unroll
    for (int n = 0; n < NF; ++n) {
        const int c = cB + wc * WN + n * 16 + r16;
        vj[n] = (c < C);
        bj[n] = (vj[n] && bias) ? bias[c] : 0.f;
    }

    if (c0cap != nullptr && cB + BN > 4000) {
        #pragma unroll
        for (int n = 0; n < NF; ++n) {
            const int c = cB + wc * WN + n * 16 + r16;
            if (c == 4000 || c == 4001) {
                float* dst = (c == 4000) ? c0cap : c1cap;
                #pragma unroll
                for (int m = 0; m < MF; ++m)
                    #pragma unroll
                    for (int r = 0; r < 4; ++r) {
                        const int row = rowA0 + wr * WM + m * 16 + q16 * 4 + r;
                        dst[row] = acc[m][n][r] + bj[n];
                    }
            }
        }
    }

    __syncthreads();
    float* pl = (float*)lds;
    #pragma unroll
    for (int m = 0; m < MF; ++m)
        #pragma unroll
        for (int r = 0; r < 4; ++r) {
            float s = 0.f;
            #pragma unroll
            for (int n = 0; n < NF; ++n)
                if (vj[n]) s += __expf(acc[m][n][r] + bj[n]);
            s += __shfl_xor(s, 1); s += __shfl_xor(s, 2);
            s += __shfl_xor(s, 4); s += __shfl_xor(s, 8);
            if (r16 == 0)
                pl[wc * BM + wr * WM + m * 16 + q16 * 4 + r] = s;
        }
    __syncthreads();
    if (tid < BM)
        part[(size_t)by * N_ROWS + rowA0 + tid] =
            pl[tid] + pl[BM + tid] + pl[2 * BM + tid] + pl[3 * BM + tid];
}

// ---------------------------------------------------------------------------
// TAIL0: same 8-wave <128,256> ring body, flat-pipelined over CTILES col-tiles
// per block (8 flat steps: pipeline stays warm across tiles; esum accumulated
// in REGISTERS across tiles, single LDS reduce at end). K=256, C=16000.
// Grid (16, 32): by covers CTILES*256=512 cols -> part dim 32.
// ---------------------------------------------------------------------------
template<int CTILES>
__global__ __launch_bounds__(512, 2) void tail0_kernel(
    const unsigned short* __restrict__ A,   // [2048][256]
    const unsigned short* __restrict__ W,   // [16000][256]
    float* __restrict__ part)
{
    constexpr int BM = 128, BN = 256, K = 256, C = 16000;
    constexpr int NT = 4;                   // K / 64
    constexpr int WM = 64, WN = 64, MF = 4, NF = 4, NA = 2, NB = 4, L = 6;
    constexpr int ABYTES   = BM * 128;
    constexpr int BUFBYTES = (BM + BN) * 128;
    constexpr int S = CTILES * NT;
    __shared__ char lds[3 * BUFBYTES];

    const int gx = gridDim.x, gy = gridDim.y;
    const int nwg = gx * gy;
    const int lid = blockIdx.x + gx * blockIdx.y;
    const int xcd = lid & 7, idx8 = lid >> 3;
    const int qq = nwg >> 3, rr = nwg & 7;
    const int wg = (xcd < rr ? xcd * (qq + 1) : rr * (qq + 1) + (xcd - rr) * qq) + idx8;
    const int bx = wg % gx;
    const int by = wg / gx;

    const int tid = threadIdx.x;
    const int w = tid >> 6, l = tid & 63;
    const int wr = w >> 2, wc = w & 3;
    const int q16 = l >> 4, r16 = l & 15;
    const int rowA0 = bx * BM;
    const int colBase = by * (CTILES * BN);

    const int srow = tid >> 3;
    const int sp   = (tid & 7) ^ (srow & 7);
    const unsigned short* aSrc[NA];
    const unsigned short* bSrc[NB];
    #pragma unroll
    for (int c = 0; c < NA; ++c)
        aSrc[c] = A + (size_t)(rowA0 + c * 64 + srow) * K + sp * 8;
    auto setB = [&](int ct) {
        #pragma unroll
        for (int c = 0; c < NB; ++c) {
            int rbl = colBase + ct * BN + c * 64 + srow;
            if (rbl >= C) rbl = C - 1;
            bSrc[c] = W + (size_t)rbl * K + sp * 8;
        }
    };

    auto stage = [&](int kt, int buf) {
        char* base = lds + buf * BUFBYTES;
        #pragma unroll
        for (int c = 0; c < NA; ++c)
            gload_lds16(aSrc[c] + kt * 64, base + c * 8192 + (w << 10));
        #pragma unroll
        for (int c = 0; c < NB; ++c)
            gload_lds16(bSrc[c] + kt * 64, base + ABYTES + c * 8192 + (w << 10));
    };

    setB(0);
    int ksS = 0, ctS = 0;
    auto advS = [&]() {
        if (++ksS == NT) { ksS = 0; ++ctS; if (ctS < CTILES) setB(ctS); }
    };
    stage(ksS, 0); advS();
    stage(ksS, 1); advS();

    float esum[MF][4];
    #pragma unroll
    for (int m = 0; m < MF; ++m)
        #pragma unroll
        for (int r = 0; r < 4; ++r) esum[m][r] = 0.f;

    f32x4 acc[MF][NF];

    for (int s = 0; s < S; ++s) {
        const int buf = s % 3;
        const int kt = s & (NT - 1);
        const int ct = s >> 2;
        if (s + 1 < S) wait_vmcnt<L>(); else wait_vmcnt<0>();
        __builtin_amdgcn_s_barrier();
        __builtin_amdgcn_sched_barrier(0);
        if (s + 2 < S) { stage(ksS, (s + 2) % 3); advS(); }
        __builtin_amdgcn_sched_barrier(0);

        if (kt == 0) {
            #pragma unroll
            for (int m = 0; m < MF; ++m)
                #pragma unroll
                for (int n = 0; n < NF; ++n) acc[m][n] = (f32x4){0.f, 0.f, 0.f, 0.f};
        }

        const char* Ab = lds + buf * BUFBYTES;
        const char* Bb = Ab + ABYTES;
        #pragma unroll
        for (int ks = 0; ks < 2; ++ks) {
            const int xs = ((ks * 4 + q16) ^ (l & 7)) << 4;
            bf16x8 af[MF], bv[NF];
            #pragma unroll
            for (int m = 0; m < MF; ++m)
                af[m] = *reinterpret_cast<const bf16x8*>(
                    Ab + (wr * WM + m * 16 + r16) * 128 + xs);
            #pragma unroll
            for (int n = 0; n < NF; ++n)
                bv[n] = *reinterpret_cast<const bf16x8*>(
                    Bb + (wc * WN + n * 16 + r16) * 128 + xs);
            __builtin_amdgcn_s_setprio(1);
            #pragma unroll
            for (int m = 0; m < MF; ++m)
                #pragma unroll
                for (int n = 0; n < NF; ++n)
                    acc[m][n] = __builtin_amdgcn_mfma_f32_16x16x32_bf16(
                        af[m], bv[n], acc[m][n], 0, 0, 0);
            __builtin_amdgcn_s_setprio(0);
        }

        if (kt == NT - 1) {                  // register-only exp accumulate
            bool vj[NF];
            #pragma unroll
            for (int n = 0; n < NF; ++n)
                vj[n] = (colBase + ct * BN + wc * WN + n * 16 + r16) < C;
            #pragma unroll
            for (int m = 0; m < MF; ++m)
                #pragma unroll
                for (int r = 0; r < 4; ++r) {
                    float sv = 0.f;
                    #pragma unroll
                    for (int n = 0; n < NF; ++n)
                        if (vj[n]) sv += __expf(acc[m][n][r]);
                    esum[m][r] += sv;
                }
        }
    }

    __syncthreads();
    float* pl = (float*)lds;
    #pragma unroll
    for (int m = 0; m < MF; ++m)
        #pragma unroll
        for (int r = 0; r < 4; ++r) {
            float v = esum[m][r];
            v += __shfl_xor(v, 1); v += __shfl_xor(v, 2);
            v += __shfl_xor(v, 4); v += __shfl_xor(v, 8);
            if (r16 == 0)
                pl[wc * BM + wr * WM + m * 16 + q16 * 4 + r] = v;
        }
    __syncthreads();
    if (tid < BM)
        part[(size_t)by * N_ROWS + rowA0 + tid] =
            pl[tid] + pl[BM + tid] + pl[2 * BM + tid] + pl[3 * BM + tid];
}

// ---------------------------------------------------------------------------
// tail1 specialist: K=64 one tile -> pipeline along COLUMNS. A staged once,
// A-frags in registers; W streams through a 3-buf LDS ring (single barrier,
// counted vmcnt(2)). LDS 64KB -> 2 blocks/CU.
// ---------------------------------------------------------------------------
template<int CT>
__global__ __launch_bounds__(512, 4) void tail1_kernel(
    const unsigned short* __restrict__ A,   // [2048][64]
    const unsigned short* __restrict__ W,   // [C][64]
    float* __restrict__ part, int C)
{
    __shared__ char lds[65536];

    const int gx = gridDim.x, gy = gridDim.y;
    const int nwg = gx * gy;
    const int lid = blockIdx.x + gx * blockIdx.y;
    const int xcd = lid & 7, idx8 = lid >> 3;
    const int qq = nwg >> 3, rr = nwg & 7;
    const int wg = (xcd < rr ? xcd * (qq + 1) : rr * (qq + 1) + (xcd - rr) * qq) + idx8;
    const int bx = wg % gx;
    const int by = wg / gx;

    const int tid = threadIdx.x;
    const int w = tid >> 6, l = tid & 63;
    const int wr = w >> 2, wc = w & 3;      // WM=64 (MF=4), WN=32 (NF=2)
    const int q16 = l >> 4, r16 = l & 15;
    const int rowA0 = bx * 128;
    const int cB0 = by * (CT * 128);

    const int srow = tid >> 3;
    const int sp   = (tid & 7) ^ (srow & 7);

    #pragma unroll
    for (int c = 0; c < 2; ++c)
        gload_lds16(A + (size_t)(rowA0 + c * 64 + srow) * 64 + sp * 8,
                    lds + c * 8192 + (w << 10));

    auto stageW = [&](int ct, int buf) {
        char* base = lds + 16384 + buf * 16384;
        #pragma unroll
        for (int c = 0; c < 2; ++c) {
            int rw = cB0 + ct * 128 + c * 64 + srow;
            if (rw >= C) rw = C - 1;
            gload_lds16(W + (size_t)rw * 64 + sp * 8, base + c * 8192 + (w << 10));
        }
    };
    stageW(0, 0);
    if (CT > 1) stageW(1, 1);

    wait_vmcnt<4>();
    __builtin_amdgcn_s_barrier();

    bf16x8 areg[2][4];
    #pragma unroll
    for (int ks = 0; ks < 2; ++ks)
        #pragma unroll
        for (int m = 0; m < 4; ++m) {
            const int row = wr * 64 + m * 16 + r16;
            const int xs = ((ks * 4 + q16) ^ (l & 7)) << 4;
            areg[ks][m] = *reinterpret_cast<const bf16x8*>(lds + row * 128 + xs);
        }

    float esum[4][4];
    #pragma unroll
    for (int m = 0; m < 4; ++m)
        #pragma unroll
        for (int r = 0; r < 4; ++r) esum[m][r] = 0.f;

    for (int ct = 0; ct < CT; ++ct) {
        const int buf = ct % 3;
        if (ct + 1 < CT) wait_vmcnt<2>(); else wait_vmcnt<0>();
        __builtin_amdgcn_s_barrier();
        __builtin_amdgcn_sched_barrier(0);
        if (ct + 2 < CT) stageW(ct + 2, (ct + 2) % 3);
        __builtin_amdgcn_sched_barrier(0);

        const char* Bb = lds + 16384 + buf * 16384;
        bf16x8 wreg[2][2];
        #pragma unroll
        for (int ks = 0; ks < 2; ++ks)
            #pragma unroll
            for (int n = 0; n < 2; ++n) {
                const int row = wc * 32 + n * 16 + r16;
                const int xs = ((ks * 4 + q16) ^ (l & 7)) << 4;
                wreg[ks][n] = *reinterpret_cast<const bf16x8*>(Bb + row * 128 + xs);
            }

        f32x4 acc[4][2];
        #pragma unroll
        for (int m = 0; m < 4; ++m)
            #pragma unroll
            for (int n = 0; n < 2; ++n) acc[m][n] = (f32x4){0.f, 0.f, 0.f, 0.f};

        __builtin_amdgcn_s_setprio(1);
        #pragma unroll
        for (int ks = 0; ks < 2; ++ks)
            #pragma unroll
            for (int m = 0; m < 4; ++m)
                #pragma unroll
                for (int n = 0; n < 2; ++n)
                    acc[m][n] = __builtin_amdgcn_mfma_f32_16x16x32_bf16(
                        areg[ks][m], wreg[ks][n], acc[m][n], 0, 0, 0);
        __builtin_amdgcn_s_setprio(0);

        bool vj[2];
        #pragma unroll
        for (int n = 0; n < 2; ++n)
            vj[n] = (cB0 + ct * 128 + wc * 32 + n * 16 + r16) < C;
        #pragma unroll
        for (int m = 0; m < 4; ++m)
            #pragma unroll
            for (int r = 0; r < 4; ++r) {
                float s = 0.f;
                #pragma unroll
                for (int n = 0; n < 2; ++n)
                    if (vj[n]) s += __expf(acc[m][n][r]);
                esum[m][r] += s;
            }
    }

    __syncthreads();
    float* pl = (float*)lds;
    #pragma unroll
    for (int m = 0; m < 4; ++m)
        #pragma unroll
        for (int r = 0; r < 4; ++r) {
            float v = esum[m][r];
            v += __shfl_xor(v, 1); v += __shfl_xor(v, 2);
            v += __shfl_xor(v, 4); v += __shfl_xor(v, 8);
            if (r16 == 0)
                pl[wc * 128 + wr * 64 + m * 16 + q16 * 4 + r] = v;
        }
    __syncthreads();
    if (tid < 128)
        part[(size_t)by * N_ROWS + rowA0 + tid] =
            pl[tid] + pl[128 + tid] + pl[256 + tid] + pl[384 + tid];
}

// ---------------------------------------------------------------------------
// proj GEMM (128-tile ring pipeline, split-K plain stores) — proven, unchanged
// ---------------------------------------------------------------------------
template<int MODE>
__global__ __launch_bounds__(256) void gemm_pipe_kernel(
    const unsigned short* __restrict__ A, int K,
    const unsigned short* __restrict__ W, int C,
    float* __restrict__ outF, int kLen)
{
    __shared__ char lds[49152];

    const int gx = gridDim.x, gy = gridDim.y;
    const int nwg = gx * gy * gridDim.z;
    const int lid = blockIdx.x + gx * (blockIdx.y + gy * blockIdx.z);
    const int xcd = lid & 7, idx8 = lid >> 3;
    const int qq = nwg >> 3, rr = nwg & 7;
    const int wg = (xcd < rr ? xcd * (qq + 1) : rr * (qq + 1) + (xcd - rr) * qq) + idx8;
    const int bx = wg % gx;
    const int t1 = wg / gx;
    const int by = t1 % gy;
    const int bz = t1 / gy;

    const int tid = threadIdx.x;
    const int w = tid >> 6, l = tid & 63;
    const int wr = w >> 1, wc = w & 1;
    const int q16 = l >> 4, r16 = l & 15;
    const int rowA0 = bx << 7;
    const int kBeg = bz * kLen;

    const int sRl = (w << 5) + (l >> 2);
    const int sS  = l & 3;
    const int nt  = kLen >> 5;

    const unsigned short* aB[2];
    const unsigned short* wB[2];
    #pragma unroll
    for (int it = 0; it < 2; ++it) {
        const int R  = sRl + (it << 4);
        const int Sp = sS ^ ((R >> 1) & 3);
        aB[it] = A + (size_t)(rowA0 + R) * K + kBeg + Sp * 8;
        int Rw = (by << 7) + R; if (Rw >= C) Rw = C - 1;
        wB[it] = W + (size_t)Rw * K + kBeg + Sp * 8;
    }

    auto stage = [&](int ksv, int buf) {
        char* Ab = lds + buf * 16384;
        char* Wb = Ab + 8192;
        const int ko = ksv << 5;
        #pragma unroll
        for (int it = 0; it < 2; ++it) {
            gload_lds16(aB[it] + ko, Ab + (w << 11) + (it << 10));
            gload_lds16(wB[it] + ko, Wb + (w << 11) + (it << 10));
        }
    };

    f32x4 acc[4][4];
    #pragma unroll
    for (int m = 0; m < 4; ++m)
        #pragma unroll
        for (int n = 0; n < 4; ++n) acc[m][n] = (f32x4){0.f, 0.f, 0.f, 0.f};

    stage(0, 0); stage(1, 1); stage(2, 2);

    for (int s = 0; s < nt; ++s) {
        const int rem = nt - 1 - s;
        if (rem >= 2)      wait_vmcnt<8>();
        else if (rem == 1) wait_vmcnt<4>();
        else               wait_vmcnt<0>();
        __builtin_amdgcn_s_barrier();
        __builtin_amdgcn_sched_barrier(0);

        char* Ab = lds + (s % 3) * 16384;
        char* Wb = Ab + 8192;
        bf16x8 af[4], bfr[4];
        #pragma unroll
        for (int m = 0; m < 4; ++m) {
            const int row = (wr << 6) + (m << 4) + r16;
            af[m] = *reinterpret_cast<const bf16x8*>(
                Ab + row * 64 + ((q16 ^ ((row >> 1) & 3)) << 4));
        }
        #pragma unroll
        for (int n = 0; n < 4; ++n) {
            const int row = (wc << 6) + (n << 4) + r16;
            bfr[n] = *reinterpret_cast<const bf16x8*>(
                Wb + row * 64 + ((q16 ^ ((row >> 1) & 3)) << 4));
        }
        __builtin_amdgcn_sched_barrier(0);
        __builtin_amdgcn_s_barrier();

        if (s + 3 < nt) stage(s + 3, s % 3);

        __builtin_amdgcn_s_setprio(1);
        #pragma unroll
        for (int m = 0; m < 4; ++m)
            #pragma unroll
            for (int n = 0; n < 4; ++n)
                acc[m][n] = __builtin_amdgcn_mfma_f32_16x16x32_bf16(
                    af[m], bfr[n], acc[m][n], 0, 0, 0);
        __builtin_amdgcn_s_setprio(0);
    }

    float* o = outF + (size_t)bz * ((size_t)N_ROWS * C);
    #pragma unroll
    for (int n = 0; n < 4; ++n) {
        const int c = (by << 7) + (wc << 6) + (n << 4) + r16;
        if (c < C) {
            #pragma unroll
            for (int m = 0; m < 4; ++m)
                #pragma unroll
                for (int r = 0; r < 4; ++r) {
                    const int row = rowA0 + (wr << 6) + (m << 4) + (q16 << 2) + r;
                    o[(size_t)row * C + c] = acc[m][n][r];
                }
        }
    }
}

// ---------------------------------------------------------------------------
// dotfinal: per-row target dot + partial-sum reduce + log-softmax combine.
// grid 512 x 256 threads: 4 rows/block, one wave per row.
// ---------------------------------------------------------------------------
__global__ __launch_bounds__(256) void dotfinal_kernel(
    const unsigned short* __restrict__ emb,
    const unsigned short* __restrict__ headW,
    const float* __restrict__ headB,
    const unsigned short* __restrict__ h0,
    const unsigned short* __restrict__ t0out,
    const unsigned short* __restrict__ h1,
    const unsigned short* __restrict__ t1out,
    const int* __restrict__ tgt32,
    const float* __restrict__ pH, const float* __restrict__ p0,
    const float* __restrict__ p1,
    const float* __restrict__ c0, const float* __restrict__ c1,
    float* __restrict__ out, float* __restrict__ lossPart)
{
    const int n = blockIdx.x * 4 + (threadIdx.x >> 6);
    const int l = threadIdx.x & 63;
    const int t = tgt32[n];

    float sv = 0.f;
    if (t < 4000) {
        const unsigned short* e  = emb + (size_t)n * 1024;
        const unsigned short* wt = headW + (size_t)t * 1024;
        for (int i = l; i < 1024; i += 64) sv += bf2f(e[i]) * bf2f(wt[i]);
    } else if (t < 20000) {
        const unsigned short* h  = h0 + (size_t)n * 256;
        const unsigned short* ww = t0out + (size_t)(t - 4000) * 256;
        for (int i = l; i < 256; i += 64) sv += bf2f(h[i]) * bf2f(ww[i]);
    } else {
        const unsigned short* h  = h1 + (size_t)n * 64;
        const unsigned short* ww = t1out + (size_t)(t - 20000) * 64;
        sv = bf2f(h[l]) * bf2f(ww[l]);
    }

    float sH = 0.f, s0 = 0.f, s1 = 0.f;
    if (l < 16) sH = pH[(size_t)l * N_ROWS + n];
    if (l < 32) s0 = p0[(size_t)l * N_ROWS + n];
    if (l < 30) s1 = p1[(size_t)l * N_ROWS + n];

    #pragma unroll
    for (int msk = 1; msk < 64; msk <<= 1) {
        sv += __shfl_xor(sv, msk);
        sH += __shfl_xor(sH, msk);
        s0 += __shfl_xor(s0, msk);
        s1 += __shfl_xor(s1, msk);
    }

    __shared__ float sO[4];
    if (l == 0) {
        const float lseH = logf(sH);
        float o;
        if (t < 4000)        o = (sv + headB[t]) - lseH;
        else if (t < 20000)  o = (c0[n] - lseH) + sv - logf(s0);
        else                 o = (c1[n] - lseH) + sv - logf(s1);
        out[n] = o;
        sO[threadIdx.x >> 6] = o;
    }
    __syncthreads();
    if (threadIdx.x == 0)
        lossPart[blockIdx.x] = sO[0] + sO[1] + sO[2] + sO[3];
}

// ---------------------------------------------------------------------------
__global__ __launch_bounds__(256) void finalize2_kernel(
    const float* __restrict__ lossPart, float* __restrict__ out)
{
    const int tid = threadIdx.x;
    float v = lossPart[tid] + lossPart[tid + 256];
    #pragma unroll
    for (int msk = 1; msk < 64; msk <<= 1) v += __shfl_xor(v, msk);
    __shared__ float ws4[4];
    if ((tid & 63) == 0) ws4[tid >> 6] = v;
    __syncthreads();
    if (tid == 0) out[N_ROWS] = -(ws4[0] + ws4[1] + ws4[2] + ws4[3]) / (float)N_ROWS;
}

// ---------------------------------------------------------------------------
extern "C" void kernel_launch(void* const* d_in, const int* in_sizes, int n_in,
                              void* d_out, int out_size, void* d_ws, size_t ws_size,
                              hipStream_t stream)
{
    const unsigned char* traw = (const unsigned char*)d_in[0];
    const float* lhs    = (const float*)d_in[1];
    const float* cls    = (const float*)d_in[2];
    const int*   bids   = (const int*)d_in[3];
    const int*   toks   = (const int*)d_in[4];
    const unsigned char* mraw = (const unsigned char*)d_in[5];
    const float* headW  = (const float*)d_in[6];
    const float* headB  = (const float*)d_in[7];
    const float* t0proj = (const float*)d_in[8];
    const float* t0out  = (const float*)d_in[9];
    const float* t1proj = (const float*)d_in[10];
    const float* t1out  = (const float*)d_in[11];

    char* ws = (char*)d_ws;
    unsigned short* emb_bf   = (unsigned short*)(ws + 0);          //  4,194,304
    unsigned short* headW_bf = (unsigned short*)(ws + 4194304);    //  8,196,096
    unsigned short* t0out_bf = (unsigned short*)(ws + 12390400);   //  8,192,000
    unsigned short* t1out_bf = (unsigned short*)(ws + 20582400);   //  3,840,000
    unsigned short* projcat  = (unsigned short*)(ws + 24422400);   //    655,360
    float*          h01p     = (float*)(ws + 25077760);            // 10,485,760 (4 slices)
    unsigned short* h0_bf    = (unsigned short*)(ws + 35563520);   //  1,048,576
    unsigned short* h1_bf    = (unsigned short*)(ws + 36612096);   //    262,144
    int*   tgt32  = (int*)(ws + 36874240);
    float* seH_p  = (float*)(ws + 36890624);   //  16*2048*4 =   131,072
    float* se0_p  = (float*)(ws + 37152768);   //  32*2048*4 =   262,144
    float* se1_p  = (float*)(ws + 38176768);   //  30*2048*4 =   245,760
    float* c0     = (float*)(ws + 40134656);
    float* c1     = (float*)(ws + 40142848);
    float* lossPart = (float*)(ws + 40159232); // 512*4

    // weight convert (0..2047) + targets sniff (2048) + gather (2049..4096)
    cvtgather_kernel<<<4097, 256, 0, stream>>>(
        headW, headW_bf, t0out, t0out_bf, t1out, t1out_bf,
        t0proj, projcat, t1proj, projcat + 262144,
        traw, mraw, tgt32, lhs, cls, bids, toks, emb_bf);

    // proj GEMM: h01 = emb @ [t0proj;t1proj]^T  (C=320, split-K z=4 x kLen=256)
    gemm_pipe_kernel<2><<<dim3(16, 3, 4), 256, 0, stream>>>(
        emb_bf, 1024, projcat, 320, h01p, 256);
    cvt_h01_kernel<<<2560, 256, 0, stream>>>(h01p, h0_bf, h1_bf);

    // head: BM=128 BN=256, grid (16,16)=256 blocks, NT=16 (+ c0/c1 capture)
    gemm8w_kernel<128, 256><<<dim3(16, 16), 512, 0, stream>>>(
        emb_bf, 1024, headW_bf, 4002, headB, seH_p, 16, c0, c1);
    // tail0: flat-ring, 2 col-tiles/block, grid (16,32)=512 blocks (8 steps)
    tail0_kernel<2><<<dim3(16, 32), 512, 0, stream>>>(
        h0_bf, t0out_bf, se0_p);
    // tail1 specialist: CT=8, grid (16,30)=480 blocks, 2 blocks/CU
    tail1_kernel<8><<<dim3(16, 30), 512, 0, stream>>>(
        h1_bf, t1out_bf, se1_p, 30000);

    dotfinal_kernel<<<512, 256, 0, stream>>>(
        emb_bf, headW_bf, headB, h0_bf, t0out_bf, h1_bf, t1out_bf, tgt32,
        seH_p, se0_p, se1_p, c0, c1, (float*)d_out, lossPart);
    finalize2_kernel<<<1, 256, 0, stream>>>(lossPart, (float*)d_out);
}

// Round 15
// 99.847 us; speedup vs baseline: 1.6231x; 1.0177x over previous
//
#include <hip/hip_runtime.h>
#include <cstdint>
#include <cstddef>

#define N_ROWS 2048
#define D_DIM  1024

typedef __bf16 bf16x8 __attribute__((ext_vector_type(8)));
typedef float  f32x4  __attribute__((ext_vector_type(4)));

__device__ __forceinline__ unsigned short f2bf(float f) {
    unsigned int u = __float_as_uint(f);
    unsigned int r = (u + 0x7fffu + ((u >> 16) & 1u)) >> 16;   // RNE
    return (unsigned short)r;
}
__device__ __forceinline__ float bf2f(unsigned short u) {
    return __uint_as_float(((unsigned int)u) << 16);
}
__device__ __forceinline__ void gload_lds16(const void* g, void* lds) {
    __builtin_amdgcn_global_load_lds(
        (const __attribute__((address_space(1))) unsigned int*)g,
        (__attribute__((address_space(3))) unsigned int*)lds, 16, 0, 0);
}

template<int N> __device__ __forceinline__ void wait_vmcnt();
template<> __device__ __forceinline__ void wait_vmcnt<0>() { asm volatile("s_waitcnt vmcnt(0)" ::: "memory"); }
template<> __device__ __forceinline__ void wait_vmcnt<2>() { asm volatile("s_waitcnt vmcnt(2)" ::: "memory"); }
template<> __device__ __forceinline__ void wait_vmcnt<4>() { asm volatile("s_waitcnt vmcnt(4)" ::: "memory"); }
template<> __device__ __forceinline__ void wait_vmcnt<6>() { asm volatile("s_waitcnt vmcnt(6)" ::: "memory"); }
template<> __device__ __forceinline__ void wait_vmcnt<8>() { asm volatile("s_waitcnt vmcnt(8)" ::: "memory"); }

// ---------------------------------------------------------------------------
// blocks 0..2047   : fp32->bf16 convert of all five weight tensors
// block 2048       : targets int32/int64 sniff + normalize -> tgt32
// blocks 2049..4096: gather row (b-2049): emb = replace ? cls : lhs, ->bf16.
//                    mask layout self-detected via 2KB scan (L2-hit).
// ---------------------------------------------------------------------------
__global__ __launch_bounds__(256) void cvtgather_kernel(
    const float* __restrict__ s0, unsigned short* __restrict__ d0,  // headW  4002*1024
    const float* __restrict__ s1, unsigned short* __restrict__ d1,  // t0out 16000*256
    const float* __restrict__ s2, unsigned short* __restrict__ d2,  // t1out 30000*64
    const float* __restrict__ s3, unsigned short* __restrict__ d3,  // t0proj  256*1024
    const float* __restrict__ s4, unsigned short* __restrict__ d4,  // t1proj   64*1024
    const unsigned char* __restrict__ traw,
    const unsigned char* __restrict__ mraw,
    int* __restrict__ tgt32,
    const float* __restrict__ lhs, const float* __restrict__ cls,
    const int* __restrict__ bids, const int* __restrict__ toks,
    unsigned short* __restrict__ emb)
{
    const int tid = threadIdx.x;
    const int blk = blockIdx.x;

    if (blk < 2048) {                       // weight convert
        const int total = 2610432;          // vec4 units
        for (int i = blk * 256 + tid; i < total; i += 2048 * 256) {
            const float* s; unsigned short* d; int off;
            if (i < 1024512)      { s = s0; d = d0; off = i; }
            else if (i < 2048512) { s = s1; d = d1; off = i - 1024512; }
            else if (i < 2528512) { s = s2; d = d2; off = i - 2048512; }
            else if (i < 2594048) { s = s3; d = d3; off = i - 2528512; }
            else                  { s = s4; d = d4; off = i - 2594048; }
            float4 v = ((const float4*)s)[off];
            ushort4 o;
            o.x = f2bf(v.x); o.y = f2bf(v.y); o.z = f2bf(v.z); o.w = f2bf(v.w);
            ((ushort4*)d)[off] = o;
        }
        return;
    }

    if (blk == 2048) {                      // targets sniff + normalize
        __shared__ int fOdd;
        if (tid == 0) fOdd = 0;
        __syncthreads();
        const unsigned int* tw = (const unsigned int*)traw;
        for (int i = tid; i < N_ROWS; i += 256)
            if ((i & 1) && tw[i] != 0u) atomicOr(&fOdd, 1);
        __syncthreads();
        const int tis64 = fOdd ? 0 : 1;
        for (int i = tid; i < N_ROWS; i += 256) {
            long long t = tis64 ? ((const long long*)traw)[i]
                                : (long long)((const int*)traw)[i];
            tgt32[i] = (int)t;
        }
        return;
    }

    // gather (self-detecting mask layout)
    __shared__ int fFloat, fByte;
    if (tid == 0) { fFloat = 0; fByte = 0; }
    __syncthreads();
    const unsigned int* mw = (const unsigned int*)mraw;
    for (int i = tid; i < 512; i += 256) {
        unsigned int w2 = mw[i];
        if (w2 == 0x3f800000u) atomicOr(&fFloat, 1);
        if (w2 & 0xFFFFFF00u)  atomicOr(&fByte, 1);
    }
    __syncthreads();
    const int n = blk - 2049;
    int m;
    if (!fFloat && fByte) m = (mraw[n] != 0);
    else                  m = (mw[n] != 0);
    const int b = bids[n];
    const int tok = toks[n];
    const float* src = m ? (cls + (size_t)b * D_DIM)
                         : (lhs + ((size_t)b * 512 + (size_t)tok) * D_DIM);
    float4 v = ((const float4*)src)[tid];
    ushort4 o;
    o.x = f2bf(v.x); o.y = f2bf(v.y); o.z = f2bf(v.z); o.w = f2bf(v.w);
    ((ushort4*)(emb + (size_t)n * D_DIM))[tid] = o;
}

// sum 4 split-K partials, split h01 [2048][320] -> h0 bf16 [2048][256], h1 [2048][64]
__global__ __launch_bounds__(256) void cvt_h01_kernel(
    const float* __restrict__ h01p, unsigned short* __restrict__ h0,
    unsigned short* __restrict__ h1)
{
    const int idx = blockIdx.x * 256 + threadIdx.x;
    if (idx >= 2048 * 320) return;
    const float v = h01p[idx] + h01p[655360 + idx] + h01p[1310720 + idx]
                  + h01p[1966080 + idx];
    const int r = idx / 320;
    const int c = idx - r * 320;
    const unsigned short b = f2bf(v);
    if (c < 256) h0[r * 256 + c] = b;
    else         h1[r * 64 + (c - 256)] = b;
}

// ---------------------------------------------------------------------------
// HEAD: 8-wave <128,256> GEMM, 3-deep LDS ring, ONE barrier per K-tile
// (R11-proven). Fused sum(exp(logit+bias)) -> part; c0/c1 capture
// (block-uniform: only the cB=3840 block).
// ---------------------------------------------------------------------------
template<int BM, int BN>
__global__ __launch_bounds__(512, 2) void gemm8w_kernel(
    const unsigned short* __restrict__ A, int K,
    const unsigned short* __restrict__ W, int C,
    const float* __restrict__ bias,
    float* __restrict__ part, int NT,
    float* __restrict__ c0cap, float* __restrict__ c1cap)
{
    constexpr int WM = BM / 2, WN = BN / 4;
    constexpr int MF = WM / 16, NF = WN / 16;
    constexpr int NA = BM / 64, NB = BN / 64;
    constexpr int L  = NA + NB;
    constexpr int ABYTES   = BM * 128;
    constexpr int BUFBYTES = (BM + BN) * 128;
    __shared__ char lds[3 * BUFBYTES];

    const int gx = gridDim.x, gy = gridDim.y;
    const int nwg = gx * gy;
    const int lid = blockIdx.x + gx * blockIdx.y;
    const int xcd = lid & 7, idx8 = lid >> 3;
    const int qq = nwg >> 3, rr = nwg & 7;
    const int wg = (xcd < rr ? xcd * (qq + 1) : rr * (qq + 1) + (xcd - rr) * qq) + idx8;
    const int bx = wg % gx;
    const int by = wg / gx;

    const int tid = threadIdx.x;
    const int w = tid >> 6, l = tid & 63;
    const int wr = w >> 2, wc = w & 3;
    const int q16 = l >> 4, r16 = l & 15;
    const int rowA0 = bx * BM;
    const int cB = by * BN;

    const int srow = tid >> 3;
    const int sp   = (tid & 7) ^ (srow & 7);
    const unsigned short* aSrc[NA];
    const unsigned short* bSrc[NB];
    #pragma unroll
    for (int c = 0; c < NA; ++c)
        aSrc[c] = A + (size_t)(rowA0 + c * 64 + srow) * K + sp * 8;
    #pragma unroll
    for (int c = 0; c < NB; ++c) {
        int rbl = cB + c * 64 + srow;
        if (rbl >= C) rbl = C - 1;
        bSrc[c] = W + (size_t)rbl * K + sp * 8;
    }

    auto stage = [&](int kt, int buf) {
        char* base = lds + buf * BUFBYTES;
        #pragma unroll
        for (int c = 0; c < NA; ++c)
            gload_lds16(aSrc[c] + kt * 64, base + c * 8192 + (w << 10));
        #pragma unroll
        for (int c = 0; c < NB; ++c)
            gload_lds16(bSrc[c] + kt * 64, base + ABYTES + c * 8192 + (w << 10));
    };

    f32x4 acc[MF][NF];
    #pragma unroll
    for (int m = 0; m < MF; ++m)
        #pragma unroll
        for (int n = 0; n < NF; ++n) acc[m][n] = (f32x4){0.f, 0.f, 0.f, 0.f};

    stage(0, 0);
    if (NT > 1) stage(1, 1);

    for (int kt = 0; kt < NT; ++kt) {
        const int buf = kt % 3;
        if (kt + 1 < NT) wait_vmcnt<L>(); else wait_vmcnt<0>();
        __builtin_amdgcn_s_barrier();
        __builtin_amdgcn_sched_barrier(0);
        if (kt + 2 < NT) stage(kt + 2, (kt + 2) % 3);
        __builtin_amdgcn_sched_barrier(0);

        const char* Ab = lds + buf * BUFBYTES;
        const char* Bb = Ab + ABYTES;
        #pragma unroll
        for (int ks = 0; ks < 2; ++ks) {
            const int xs = ((ks * 4 + q16) ^ (l & 7)) << 4;
            bf16x8 af[MF], bv[NF];
            #pragma unroll
            for (int m = 0; m < MF; ++m)
                af[m] = *reinterpret_cast<const bf16x8*>(
                    Ab + (wr * WM + m * 16 + r16) * 128 + xs);
            #pragma unroll
            for (int n = 0; n < NF; ++n)
                bv[n] = *reinterpret_cast<const bf16x8*>(
                    Bb + (wc * WN + n * 16 + r16) * 128 + xs);
            __builtin_amdgcn_s_setprio(1);
            #pragma unroll
            for (int m = 0; m < MF; ++m)
                #pragma unroll
                for (int n = 0; n < NF; ++n)
                    acc[m][n] = __builtin_amdgcn_mfma_f32_16x16x32_bf16(
                        af[m], bv[n], acc[m][n], 0, 0, 0);
            __builtin_amdgcn_s_setprio(0);
        }
    }

    float bj[NF]; bool vj[NF];
    #pragma unroll
    for (int n = 0; n < NF; ++n) {
        const int c = cB + wc * WN + n * 16 + r16;
        vj[n] = (c < C);
        bj[n] = (vj[n] && bias) ? bias[c] : 0.f;
    }

    if (c0cap != nullptr && cB + BN > 4000) {
        #pragma unroll
        for (int n = 0; n < NF; ++n) {
            const int c = cB + wc * WN + n * 16 + r16;
            if (c == 4000 || c == 4001) {
                float* dst = (c == 4000) ? c0cap : c1cap;
                #pragma unroll
                for (int m = 0; m < MF; ++m)
                    #pragma unroll
                    for (int r = 0; r < 4; ++r) {
                        const int row = rowA0 + wr * WM + m * 16 + q16 * 4 + r;
                        dst[row] = acc[m][n][r] + bj[n];
                    }
            }
        }
    }

    __syncthreads();
    float* pl = (float*)lds;
    #pragma unroll
    for (int m = 0; m < MF; ++m)
        #pragma unroll
        for (int r = 0; r < 4; ++r) {
            float s = 0.f;
            #pragma unroll
            for (int n = 0; n < NF; ++n)
                if (vj[n]) s += __expf(acc[m][n][r] + bj[n]);
            s += __shfl_xor(s, 1); s += __shfl_xor(s, 2);
            s += __shfl_xor(s, 4); s += __shfl_xor(s, 8);
            if (r16 == 0)
                pl[wc * BM + wr * WM + m * 16 + q16 * 4 + r] = s;
        }
    __syncthreads();
    if (tid < BM)
        part[(size_t)by * N_ROWS + rowA0 + tid] =
            pl[tid] + pl[BM + tid] + pl[2 * BM + tid] + pl[3 * BM + tid];
}

// ---------------------------------------------------------------------------
// TAIL0: 8-wave <128,256> ring body, flat-pipelined over CTILES col-tiles per
// block (pipeline stays warm; esum accumulated in REGISTERS across tiles).
// K=256, C=16000. CTILES=4 -> grid (16,16)=256 blocks, 16 flat steps/block.
// ---------------------------------------------------------------------------
template<int CTILES>
__global__ __launch_bounds__(512, 2) void tail0_kernel(
    const unsigned short* __restrict__ A,   // [2048][256]
    const unsigned short* __restrict__ W,   // [16000][256]
    float* __restrict__ part)
{
    constexpr int BM = 128, BN = 256, K = 256, C = 16000;
    constexpr int NT = 4;                   // K / 64
    constexpr int WM = 64, WN = 64, MF = 4, NF = 4, NA = 2, NB = 4, L = 6;
    constexpr int ABYTES   = BM * 128;
    constexpr int BUFBYTES = (BM + BN) * 128;
    constexpr int S = CTILES * NT;
    __shared__ char lds[3 * BUFBYTES];

    const int gx = gridDim.x, gy = gridDim.y;
    const int nwg = gx * gy;
    const int lid = blockIdx.x + gx * blockIdx.y;
    const int xcd = lid & 7, idx8 = lid >> 3;
    const int qq = nwg >> 3, rr = nwg & 7;
    const int wg = (xcd < rr ? xcd * (qq + 1) : rr * (qq + 1) + (xcd - rr) * qq) + idx8;
    const int bx = wg % gx;
    const int by = wg / gx;

    const int tid = threadIdx.x;
    const int w = tid >> 6, l = tid & 63;
    const int wr = w >> 2, wc = w & 3;
    const int q16 = l >> 4, r16 = l & 15;
    const int rowA0 = bx * BM;
    const int colBase = by * (CTILES * BN);

    const int srow = tid >> 3;
    const int sp   = (tid & 7) ^ (srow & 7);
    const unsigned short* aSrc[NA];
    const unsigned short* bSrc[NB];
    #pragma unroll
    for (int c = 0; c < NA; ++c)
        aSrc[c] = A + (size_t)(rowA0 + c * 64 + srow) * K + sp * 8;
    auto setB = [&](int ct) {
        #pragma unroll
        for (int c = 0; c < NB; ++c) {
            int rbl = colBase + ct * BN + c * 64 + srow;
            if (rbl >= C) rbl = C - 1;
            bSrc[c] = W + (size_t)rbl * K + sp * 8;
        }
    };

    auto stage = [&](int kt, int buf) {
        char* base = lds + buf * BUFBYTES;
        #pragma unroll
        for (int c = 0; c < NA; ++c)
            gload_lds16(aSrc[c] + kt * 64, base + c * 8192 + (w << 10));
        #pragma unroll
        for (int c = 0; c < NB; ++c)
            gload_lds16(bSrc[c] + kt * 64, base + ABYTES + c * 8192 + (w << 10));
    };

    setB(0);
    int ksS = 0, ctS = 0;
    auto advS = [&]() {
        if (++ksS == NT) { ksS = 0; ++ctS; if (ctS < CTILES) setB(ctS); }
    };
    stage(ksS, 0); advS();
    stage(ksS, 1); advS();

    float esum[MF][4];
    #pragma unroll
    for (int m = 0; m < MF; ++m)
        #pragma unroll
        for (int r = 0; r < 4; ++r) esum[m][r] = 0.f;

    f32x4 acc[MF][NF];

    for (int s = 0; s < S; ++s) {
        const int buf = s % 3;
        const int kt = s & (NT - 1);
        const int ct = s >> 2;
        if (s + 1 < S) wait_vmcnt<L>(); else wait_vmcnt<0>();
        __builtin_amdgcn_s_barrier();
        __builtin_amdgcn_sched_barrier(0);
        if (s + 2 < S) { stage(ksS, (s + 2) % 3); advS(); }
        __builtin_amdgcn_sched_barrier(0);

        if (kt == 0) {
            #pragma unroll
            for (int m = 0; m < MF; ++m)
                #pragma unroll
                for (int n = 0; n < NF; ++n) acc[m][n] = (f32x4){0.f, 0.f, 0.f, 0.f};
        }

        const char* Ab = lds + buf * BUFBYTES;
        const char* Bb = Ab + ABYTES;
        #pragma unroll
        for (int ks = 0; ks < 2; ++ks) {
            const int xs = ((ks * 4 + q16) ^ (l & 7)) << 4;
            bf16x8 af[MF], bv[NF];
            #pragma unroll
            for (int m = 0; m < MF; ++m)
                af[m] = *reinterpret_cast<const bf16x8*>(
                    Ab + (wr * WM + m * 16 + r16) * 128 + xs);
            #pragma unroll
            for (int n = 0; n < NF; ++n)
                bv[n] = *reinterpret_cast<const bf16x8*>(
                    Bb + (wc * WN + n * 16 + r16) * 128 + xs);
            __builtin_amdgcn_s_setprio(1);
            #pragma unroll
            for (int m = 0; m < MF; ++m)
                #pragma unroll
                for (int n = 0; n < NF; ++n)
                    acc[m][n] = __builtin_amdgcn_mfma_f32_16x16x32_bf16(
                        af[m], bv[n], acc[m][n], 0, 0, 0);
            __builtin_amdgcn_s_setprio(0);
        }

        if (kt == NT - 1) {                  // register-only exp accumulate
            bool vj[NF];
            #pragma unroll
            for (int n = 0; n < NF; ++n)
                vj[n] = (colBase + ct * BN + wc * WN + n * 16 + r16) < C;
            #pragma unroll
            for (int m = 0; m < MF; ++m)
                #pragma unroll
                for (int r = 0; r < 4; ++r) {
                    float sv = 0.f;
                    #pragma unroll
                    for (int n = 0; n < NF; ++n)
                        if (vj[n]) sv += __expf(acc[m][n][r]);
                    esum[m][r] += sv;
                }
        }
    }

    __syncthreads();
    float* pl = (float*)lds;
    #pragma unroll
    for (int m = 0; m < MF; ++m)
        #pragma unroll
        for (int r = 0; r < 4; ++r) {
            float v = esum[m][r];
            v += __shfl_xor(v, 1); v += __shfl_xor(v, 2);
            v += __shfl_xor(v, 4); v += __shfl_xor(v, 8);
            if (r16 == 0)
                pl[wc * BM + wr * WM + m * 16 + q16 * 4 + r] = v;
        }
    __syncthreads();
    if (tid < BM)
        part[(size_t)by * N_ROWS + rowA0 + tid] =
            pl[tid] + pl[BM + tid] + pl[2 * BM + tid] + pl[3 * BM + tid];
}

// ---------------------------------------------------------------------------
// tail1 specialist: K=64 one tile -> pipeline along COLUMNS. A staged once,
// A-frags in registers; W streams through a 3-buf LDS ring (single barrier,
// counted vmcnt(2)). LDS 64KB -> 2 blocks/CU.
// ---------------------------------------------------------------------------
template<int CT>
__global__ __launch_bounds__(512, 4) void tail1_kernel(
    const unsigned short* __restrict__ A,   // [2048][64]
    const unsigned short* __restrict__ W,   // [C][64]
    float* __restrict__ part, int C)
{
    __shared__ char lds[65536];

    const int gx = gridDim.x, gy = gridDim.y;
    const int nwg = gx * gy;
    const int lid = blockIdx.x + gx * blockIdx.y;
    const int xcd = lid & 7, idx8 = lid >> 3;
    const int qq = nwg >> 3, rr = nwg & 7;
    const int wg = (xcd < rr ? xcd * (qq + 1) : rr * (qq + 1) + (xcd - rr) * qq) + idx8;
    const int bx = wg % gx;
    const int by = wg / gx;

    const int tid = threadIdx.x;
    const int w = tid >> 6, l = tid & 63;
    const int wr = w >> 2, wc = w & 3;      // WM=64 (MF=4), WN=32 (NF=2)
    const int q16 = l >> 4, r16 = l & 15;
    const int rowA0 = bx * 128;
    const int cB0 = by * (CT * 128);

    const int srow = tid >> 3;
    const int sp   = (tid & 7) ^ (srow & 7);

    #pragma unroll
    for (int c = 0; c < 2; ++c)
        gload_lds16(A + (size_t)(rowA0 + c * 64 + srow) * 64 + sp * 8,
                    lds + c * 8192 + (w << 10));

    auto stageW = [&](int ct, int buf) {
        char* base = lds + 16384 + buf * 16384;
        #pragma unroll
        for (int c = 0; c < 2; ++c) {
            int rw = cB0 + ct * 128 + c * 64 + srow;
            if (rw >= C) rw = C - 1;
            gload_lds16(W + (size_t)rw * 64 + sp * 8, base + c * 8192 + (w << 10));
        }
    };
    stageW(0, 0);
    if (CT > 1) stageW(1, 1);

    wait_vmcnt<4>();
    __builtin_amdgcn_s_barrier();

    bf16x8 areg[2][4];
    #pragma unroll
    for (int ks = 0; ks < 2; ++ks)
        #pragma unroll
        for (int m = 0; m < 4; ++m) {
            const int row = wr * 64 + m * 16 + r16;
            const int xs = ((ks * 4 + q16) ^ (l & 7)) << 4;
            areg[ks][m] = *reinterpret_cast<const bf16x8*>(lds + row * 128 + xs);
        }

    float esum[4][4];
    #pragma unroll
    for (int m = 0; m < 4; ++m)
        #pragma unroll
        for (int r = 0; r < 4; ++r) esum[m][r] = 0.f;

    for (int ct = 0; ct < CT; ++ct) {
        const int buf = ct % 3;
        if (ct + 1 < CT) wait_vmcnt<2>(); else wait_vmcnt<0>();
        __builtin_amdgcn_s_barrier();
        __builtin_amdgcn_sched_barrier(0);
        if (ct + 2 < CT) stageW(ct + 2, (ct + 2) % 3);
        __builtin_amdgcn_sched_barrier(0);

        const char* Bb = lds + 16384 + buf * 16384;
        bf16x8 wreg[2][2];
        #pragma unroll
        for (int ks = 0; ks < 2; ++ks)
            #pragma unroll
            for (int n = 0; n < 2; ++n) {
                const int row = wc * 32 + n * 16 + r16;
                const int xs = ((ks * 4 + q16) ^ (l & 7)) << 4;
                wreg[ks][n] = *reinterpret_cast<const bf16x8*>(Bb + row * 128 + xs);
            }

        f32x4 acc[4][2];
        #pragma unroll
        for (int m = 0; m < 4; ++m)
            #pragma unroll
            for (int n = 0; n < 2; ++n) acc[m][n] = (f32x4){0.f, 0.f, 0.f, 0.f};

        __builtin_amdgcn_s_setprio(1);
        #pragma unroll
        for (int ks = 0; ks < 2; ++ks)
            #pragma unroll
            for (int m = 0; m < 4; ++m)
                #pragma unroll
                for (int n = 0; n < 2; ++n)
                    acc[m][n] = __builtin_amdgcn_mfma_f32_16x16x32_bf16(
                        areg[ks][m], wreg[ks][n], acc[m][n], 0, 0, 0);
        __builtin_amdgcn_s_setprio(0);

        bool vj[2];
        #pragma unroll
        for (int n = 0; n < 2; ++n)
            vj[n] = (cB0 + ct * 128 + wc * 32 + n * 16 + r16) < C;
        #pragma unroll
        for (int m = 0; m < 4; ++m)
            #pragma unroll
            for (int r = 0; r < 4; ++r) {
                float s = 0.f;
                #pragma unroll
                for (int n = 0; n < 2; ++n)
                    if (vj[n]) s += __expf(acc[m][n][r]);
                esum[m][r] += s;
            }
    }

    __syncthreads();
    float* pl = (float*)lds;
    #pragma unroll
    for (int m = 0; m < 4; ++m)
        #pragma unroll
        for (int r = 0; r < 4; ++r) {
            float v = esum[m][r];
            v += __shfl_xor(v, 1); v += __shfl_xor(v, 2);
            v += __shfl_xor(v, 4); v += __shfl_xor(v, 8);
            if (r16 == 0)
                pl[wc * 128 + wr * 64 + m * 16 + q16 * 4 + r] = v;
        }
    __syncthreads();
    if (tid < 128)
        part[(size_t)by * N_ROWS + rowA0 + tid] =
            pl[tid] + pl[128 + tid] + pl[256 + tid] + pl[384 + tid];
}

// ---------------------------------------------------------------------------
// proj GEMM (128-tile ring pipeline, split-K plain stores) — proven, unchanged
// ---------------------------------------------------------------------------
template<int MODE>
__global__ __launch_bounds__(256) void gemm_pipe_kernel(
    const unsigned short* __restrict__ A, int K,
    const unsigned short* __restrict__ W, int C,
    float* __restrict__ outF, int kLen)
{
    __shared__ char lds[49152];

    const int gx = gridDim.x, gy = gridDim.y;
    const int nwg = gx * gy * gridDim.z;
    const int lid = blockIdx.x + gx * (blockIdx.y + gy * blockIdx.z);
    const int xcd = lid & 7, idx8 = lid >> 3;
    const int qq = nwg >> 3, rr = nwg & 7;
    const int wg = (xcd < rr ? xcd * (qq + 1) : rr * (qq + 1) + (xcd - rr) * qq) + idx8;
    const int bx = wg % gx;
    const int t1 = wg / gx;
    const int by = t1 % gy;
    const int bz = t1 / gy;

    const int tid = threadIdx.x;
    const int w = tid >> 6, l = tid & 63;
    const int wr = w >> 1, wc = w & 1;
    const int q16 = l >> 4, r16 = l & 15;
    const int rowA0 = bx << 7;
    const int kBeg = bz * kLen;

    const int sRl = (w << 5) + (l >> 2);
    const int sS  = l & 3;
    const int nt  = kLen >> 5;

    const unsigned short* aB[2];
    const unsigned short* wB[2];
    #pragma unroll
    for (int it = 0; it < 2; ++it) {
        const int R  = sRl + (it << 4);
        const int Sp = sS ^ ((R >> 1) & 3);
        aB[it] = A + (size_t)(rowA0 + R) * K + kBeg + Sp * 8;
        int Rw = (by << 7) + R; if (Rw >= C) Rw = C - 1;
        wB[it] = W + (size_t)Rw * K + kBeg + Sp * 8;
    }

    auto stage = [&](int ksv, int buf) {
        char* Ab = lds + buf * 16384;
        char* Wb = Ab + 8192;
        const int ko = ksv << 5;
        #pragma unroll
        for (int it = 0; it < 2; ++it) {
            gload_lds16(aB[it] + ko, Ab + (w << 11) + (it << 10));
            gload_lds16(wB[it] + ko, Wb + (w << 11) + (it << 10));
        }
    };

    f32x4 acc[4][4];
    #pragma unroll
    for (int m = 0; m < 4; ++m)
        #pragma unroll
        for (int n = 0; n < 4; ++n) acc[m][n] = (f32x4){0.f, 0.f, 0.f, 0.f};

    stage(0, 0); stage(1, 1); stage(2, 2);

    for (int s = 0; s < nt; ++s) {
        const int rem = nt - 1 - s;
        if (rem >= 2)      wait_vmcnt<8>();
        else if (rem == 1) wait_vmcnt<4>();
        else               wait_vmcnt<0>();
        __builtin_amdgcn_s_barrier();
        __builtin_amdgcn_sched_barrier(0);

        char* Ab = lds + (s % 3) * 16384;
        char* Wb = Ab + 8192;
        bf16x8 af[4], bfr[4];
        #pragma unroll
        for (int m = 0; m < 4; ++m) {
            const int row = (wr << 6) + (m << 4) + r16;
            af[m] = *reinterpret_cast<const bf16x8*>(
                Ab + row * 64 + ((q16 ^ ((row >> 1) & 3)) << 4));
        }
        #pragma unroll
        for (int n = 0; n < 4; ++n) {
            const int row = (wc << 6) + (n << 4) + r16;
            bfr[n] = *reinterpret_cast<const bf16x8*>(
                Wb + row * 64 + ((q16 ^ ((row >> 1) & 3)) << 4));
        }
        __builtin_amdgcn_sched_barrier(0);
        __builtin_amdgcn_s_barrier();

        if (s + 3 < nt) stage(s + 3, s % 3);

        __builtin_amdgcn_s_setprio(1);
        #pragma unroll
        for (int m = 0; m < 4; ++m)
            #pragma unroll
            for (int n = 0; n < 4; ++n)
                acc[m][n] = __builtin_amdgcn_mfma_f32_16x16x32_bf16(
                    af[m], bfr[n], acc[m][n], 0, 0, 0);
        __builtin_amdgcn_s_setprio(0);
    }

    float* o = outF + (size_t)bz * ((size_t)N_ROWS * C);
    #pragma unroll
    for (int n = 0; n < 4; ++n) {
        const int c = (by << 7) + (wc << 6) + (n << 4) + r16;
        if (c < C) {
            #pragma unroll
            for (int m = 0; m < 4; ++m)
                #pragma unroll
                for (int r = 0; r < 4; ++r) {
                    const int row = rowA0 + (wr << 6) + (m << 4) + (q16 << 2) + r;
                    o[(size_t)row * C + c] = acc[m][n][r];
                }
        }
    }
}

// ---------------------------------------------------------------------------
// dotfinal: per-row target dot + partial-sum reduce + log-softmax combine.
// grid 512 x 256 threads: 4 rows/block, one wave per row.
// ---------------------------------------------------------------------------
__global__ __launch_bounds__(256) void dotfinal_kernel(
    const unsigned short* __restrict__ emb,
    const unsigned short* __restrict__ headW,
    const float* __restrict__ headB,
    const unsigned short* __restrict__ h0,
    const unsigned short* __restrict__ t0out,
    const unsigned short* __restrict__ h1,
    const unsigned short* __restrict__ t1out,
    const int* __restrict__ tgt32,
    const float* __restrict__ pH, const float* __restrict__ p0,
    const float* __restrict__ p1,
    const float* __restrict__ c0, const float* __restrict__ c1,
    float* __restrict__ out, float* __restrict__ lossPart)
{
    const int n = blockIdx.x * 4 + (threadIdx.x >> 6);
    const int l = threadIdx.x & 63;
    const int t = tgt32[n];

    float sv = 0.f;
    if (t < 4000) {
        const unsigned short* e  = emb + (size_t)n * 1024;
        const unsigned short* wt = headW + (size_t)t * 1024;
        for (int i = l; i < 1024; i += 64) sv += bf2f(e[i]) * bf2f(wt[i]);
    } else if (t < 20000) {
        const unsigned short* h  = h0 + (size_t)n * 256;
        const unsigned short* ww = t0out + (size_t)(t - 4000) * 256;
        for (int i = l; i < 256; i += 64) sv += bf2f(h[i]) * bf2f(ww[i]);
    } else {
        const unsigned short* h  = h1 + (size_t)n * 64;
        const unsigned short* ww = t1out + (size_t)(t - 20000) * 64;
        sv = bf2f(h[l]) * bf2f(ww[l]);
    }

    float sH = 0.f, s0 = 0.f, s1 = 0.f;
    if (l < 16) sH = pH[(size_t)l * N_ROWS + n];
    if (l < 16) s0 = p0[(size_t)l * N_ROWS + n];
    if (l < 30) s1 = p1[(size_t)l * N_ROWS + n];

    #pragma unroll
    for (int msk = 1; msk < 64; msk <<= 1) {
        sv += __shfl_xor(sv, msk);
        sH += __shfl_xor(sH, msk);
        s0 += __shfl_xor(s0, msk);
        s1 += __shfl_xor(s1, msk);
    }

    __shared__ float sO[4];
    if (l == 0) {
        const float lseH = logf(sH);
        float o;
        if (t < 4000)        o = (sv + headB[t]) - lseH;
        else if (t < 20000)  o = (c0[n] - lseH) + sv - logf(s0);
        else                 o = (c1[n] - lseH) + sv - logf(s1);
        out[n] = o;
        sO[threadIdx.x >> 6] = o;
    }
    __syncthreads();
    if (threadIdx.x == 0)
        lossPart[blockIdx.x] = sO[0] + sO[1] + sO[2] + sO[3];
}

// ---------------------------------------------------------------------------
__global__ __launch_bounds__(256) void finalize2_kernel(
    const float* __restrict__ lossPart, float* __restrict__ out)
{
    const int tid = threadIdx.x;
    float v = lossPart[tid] + lossPart[tid + 256];
    #pragma unroll
    for (int msk = 1; msk < 64; msk <<= 1) v += __shfl_xor(v, msk);
    __shared__ float ws4[4];
    if ((tid & 63) == 0) ws4[tid >> 6] = v;
    __syncthreads();
    if (tid == 0) out[N_ROWS] = -(ws4[0] + ws4[1] + ws4[2] + ws4[3]) / (float)N_ROWS;
}

// ---------------------------------------------------------------------------
extern "C" void kernel_launch(void* const* d_in, const int* in_sizes, int n_in,
                              void* d_out, int out_size, void* d_ws, size_t ws_size,
                              hipStream_t stream)
{
    const unsigned char* traw = (const unsigned char*)d_in[0];
    const float* lhs    = (const float*)d_in[1];
    const float* cls    = (const float*)d_in[2];
    const int*   bids   = (const int*)d_in[3];
    const int*   toks   = (const int*)d_in[4];
    const unsigned char* mraw = (const unsigned char*)d_in[5];
    const float* headW  = (const float*)d_in[6];
    const float* headB  = (const float*)d_in[7];
    const float* t0proj = (const float*)d_in[8];
    const float* t0out  = (const float*)d_in[9];
    const float* t1proj = (const float*)d_in[10];
    const float* t1out  = (const float*)d_in[11];

    char* ws = (char*)d_ws;
    unsigned short* emb_bf   = (unsigned short*)(ws + 0);          //  4,194,304
    unsigned short* headW_bf = (unsigned short*)(ws + 4194304);    //  8,196,096
    unsigned short* t0out_bf = (unsigned short*)(ws + 12390400);   //  8,192,000
    unsigned short* t1out_bf = (unsigned short*)(ws + 20582400);   //  3,840,000
    unsigned short* projcat  = (unsigned short*)(ws + 24422400);   //    655,360
    float*          h01p     = (float*)(ws + 25077760);            // 10,485,760 (4 slices)
    unsigned short* h0_bf    = (unsigned short*)(ws + 35563520);   //  1,048,576
    unsigned short* h1_bf    = (unsigned short*)(ws + 36612096);   //    262,144
    int*   tgt32  = (int*)(ws + 36874240);
    float* seH_p  = (float*)(ws + 36890624);   //  16*2048*4 =   131,072
    float* se0_p  = (float*)(ws + 37152768);   //  16*2048*4 =   131,072
    float* se1_p  = (float*)(ws + 38176768);   //  30*2048*4 =   245,760
    float* c0     = (float*)(ws + 40134656);
    float* c1     = (float*)(ws + 40142848);
    float* lossPart = (float*)(ws + 40159232); // 512*4

    // weight convert (0..2047) + targets sniff (2048) + gather (2049..4096)
    cvtgather_kernel<<<4097, 256, 0, stream>>>(
        headW, headW_bf, t0out, t0out_bf, t1out, t1out_bf,
        t0proj, projcat, t1proj, projcat + 262144,
        traw, mraw, tgt32, lhs, cls, bids, toks, emb_bf);

    // proj GEMM: h01 = emb @ [t0proj;t1proj]^T  (C=320, split-K z=4 x kLen=256)
    gemm_pipe_kernel<2><<<dim3(16, 3, 4), 256, 0, stream>>>(
        emb_bf, 1024, projcat, 320, h01p, 256);
    cvt_h01_kernel<<<2560, 256, 0, stream>>>(h01p, h0_bf, h1_bf);

    // head: BM=128 BN=256, grid (16,16)=256 blocks, NT=16 (+ c0/c1 capture)
    gemm8w_kernel<128, 256><<<dim3(16, 16), 512, 0, stream>>>(
        emb_bf, 1024, headW_bf, 4002, headB, seH_p, 16, c0, c1);
    // tail0: flat-ring, 4 col-tiles/block, grid (16,16)=256 blocks (16 steps)
    tail0_kernel<4><<<dim3(16, 16), 512, 0, stream>>>(
        h0_bf, t0out_bf, se0_p);
    // tail1 specialist: CT=8, grid (16,30)=480 blocks, 2 blocks/CU
    tail1_kernel<8><<<dim3(16, 30), 512, 0, stream>>>(
        h1_bf, t1out_bf, se1_p, 30000);

    dotfinal_kernel<<<512, 256, 0, stream>>>(
        emb_bf, headW_bf, headB, h0_bf, t0out_bf, h1_bf, t1out_bf, tgt32,
        seH_p, se0_p, se1_p, c0, c1, (float*)d_out, lossPart);
    finalize2_kernel<<<1, 256, 0, stream>>>(lossPart, (float*)d_out);
}